// Round 1
// baseline (1493.013 us; speedup 1.0000x reference)
//
#include <hip/hip_runtime.h>
#include <math.h>

#define N_NODES  100000
#define N_EDGES  1600000
#define IN_F     128
#define HID      64
#define HEADS    4
#define NCLS     16
#define D1       (HEADS*HID)    // 256
#define D2       (HEADS*NCLS)   // 64

// ============================ CSR build ============================
__global__ void k_zero_i32(int* __restrict__ p, int n) {
  int i = blockIdx.x * blockDim.x + threadIdx.x;
  if (i < n) p[i] = 0;
}

__global__ void k_count(const int* __restrict__ dst, int* __restrict__ counts) {
  int i = blockIdx.x * blockDim.x + threadIdx.x;
  if (i < N_EDGES) atomicAdd(&counts[dst[i]], 1);
}

__global__ __launch_bounds__(1024)
void k_scan(const int* __restrict__ counts, int* __restrict__ offs,
            int* __restrict__ cursor) {
  __shared__ int part[1024];
  int t = threadIdx.x;
  const int CH = (N_NODES + 1023) / 1024;   // 98
  int lo = t * CH;
  int hi = lo + CH; if (hi > N_NODES) hi = N_NODES; if (lo > N_NODES) lo = N_NODES;
  int s = 0;
  for (int i = lo; i < hi; ++i) s += counts[i];
  part[t] = s;
  __syncthreads();
  for (int o = 1; o < 1024; o <<= 1) {
    int v = (t >= o) ? part[t - o] : 0;
    __syncthreads();
    part[t] += v;
    __syncthreads();
  }
  int run = (t == 0) ? 0 : part[t - 1];   // exclusive base
  for (int i = lo; i < hi; ++i) {
    offs[i] = run; cursor[i] = run; run += counts[i];
  }
  if (t == 1023) offs[N_NODES] = run;
}

__global__ void k_scatter(const int* __restrict__ src, const int* __restrict__ dst,
                          int* __restrict__ cursor, int* __restrict__ csrsrc) {
  int i = blockIdx.x * blockDim.x + threadIdx.x;
  if (i < N_EDGES) {
    int p = atomicAdd(&cursor[dst[i]], 1);
    csrsrc[p] = src[i];
  }
}

// ============================ GEMM 1 ============================
// C[N,256] = A[N,128] * B (+bias), B[f,c] = W1[(c>>6)*8192 + f*64 + (c&63)]
#define BK 32
__global__ __launch_bounds__(256)
void k_gemm1(const float* __restrict__ A, const float* __restrict__ W,
             const float* __restrict__ bias, float* __restrict__ C) {
  __shared__ float As[BK][128 + 4];
  __shared__ float Bs[BK][128 + 4];
  int t = threadIdx.x;
  int row0 = blockIdx.x * 128;
  int col0 = blockIdx.y * 128;
  int tr = t >> 4, tc = t & 15;
  float acc[8][8] = {};
  int ar = t >> 1;             // 0..127
  int ac = (t & 1) * 16;       // 0 or 16

  for (int kk = 0; kk < IN_F; kk += BK) {
    __syncthreads();
    // --- A tile: 16 consecutive k of one row, stored transposed ---
    {
      int grow = row0 + ar;
      float av[16];
      if (grow < N_NODES) {
        const float4* ap = (const float4*)(A + (size_t)grow * IN_F + kk + ac);
        *(float4*)&av[0]  = ap[0];
        *(float4*)&av[4]  = ap[1];
        *(float4*)&av[8]  = ap[2];
        *(float4*)&av[12] = ap[3];
      } else {
        #pragma unroll
        for (int u = 0; u < 16; ++u) av[u] = 0.f;
      }
      #pragma unroll
      for (int u = 0; u < 16; ++u) As[ac + u][ar] = av[u];
    }
    // --- B tile ---
    #pragma unroll
    for (int j = 0; j < 4; ++j) {
      int s = t + j * 256;
      int f = s >> 5;           // 0..31
      int c = (s & 31) * 4;     // 0..124
      int gc = col0 + c;
      const float* wp = W + ((gc >> 6) << 13) + ((size_t)(kk + f) << 6) + (gc & 63);
      *(float4*)&Bs[f][c] = *(const float4*)wp;
    }
    __syncthreads();
    for (int k = 0; k < BK; ++k) {
      float av[8], bv[8];
      *(float4*)&av[0] = *(float4*)&As[k][tr * 8];
      *(float4*)&av[4] = *(float4*)&As[k][tr * 8 + 4];
      *(float4*)&bv[0] = *(float4*)&Bs[k][tc * 8];
      *(float4*)&bv[4] = *(float4*)&Bs[k][tc * 8 + 4];
      #pragma unroll
      for (int i = 0; i < 8; ++i)
        #pragma unroll
        for (int j = 0; j < 8; ++j)
          acc[i][j] = fmaf(av[i], bv[j], acc[i][j]);
    }
  }
  float4 bb0 = *(const float4*)&bias[col0 + tc * 8];
  float4 bb1 = *(const float4*)&bias[col0 + tc * 8 + 4];
  #pragma unroll
  for (int i = 0; i < 8; ++i) {
    int grow = row0 + tr * 8 + i;
    if (grow < N_NODES) {
      float4 o0 = make_float4(acc[i][0] + bb0.x, acc[i][1] + bb0.y,
                              acc[i][2] + bb0.z, acc[i][3] + bb0.w);
      float4 o1 = make_float4(acc[i][4] + bb1.x, acc[i][5] + bb1.y,
                              acc[i][6] + bb1.z, acc[i][7] + bb1.w);
      float4* cp = (float4*)(C + (size_t)grow * D1 + col0 + tc * 8);
      cp[0] = o0; cp[1] = o1;
    }
  }
}

// ============================ GEMM 2 ============================
// C[N,64] = A[N,256] * B (+bias), B[f,c] = W2[(c>>4)*4096 + f*16 + (c&15)]
__global__ __launch_bounds__(256)
void k_gemm2(const float* __restrict__ A, const float* __restrict__ W,
             const float* __restrict__ bias, float* __restrict__ C) {
  __shared__ float As[BK][128 + 4];
  __shared__ float Bs[BK][64 + 4];
  int t = threadIdx.x;
  int row0 = blockIdx.x * 128;
  int tr = t >> 4, tc = t & 15;       // 16 x 16 threads; 8 rows x 4 cols each
  float acc[8][4] = {};
  int ar = t >> 1;
  int ac = (t & 1) * 16;

  for (int kk = 0; kk < D1; kk += BK) {
    __syncthreads();
    {
      int grow = row0 + ar;
      float av[16];
      if (grow < N_NODES) {
        const float4* ap = (const float4*)(A + (size_t)grow * D1 + kk + ac);
        *(float4*)&av[0]  = ap[0];
        *(float4*)&av[4]  = ap[1];
        *(float4*)&av[8]  = ap[2];
        *(float4*)&av[12] = ap[3];
      } else {
        #pragma unroll
        for (int u = 0; u < 16; ++u) av[u] = 0.f;
      }
      #pragma unroll
      for (int u = 0; u < 16; ++u) As[ac + u][ar] = av[u];
    }
    #pragma unroll
    for (int j = 0; j < 2; ++j) {
      int s = t + j * 256;
      int f = s >> 4;           // 0..31
      int c = (s & 15) * 4;     // 0..60
      const float* wp = W + ((c >> 4) << 12) + ((size_t)(kk + f) << 4) + (c & 15);
      *(float4*)&Bs[f][c] = *(const float4*)wp;
    }
    __syncthreads();
    for (int k = 0; k < BK; ++k) {
      float av[8], bv[4];
      *(float4*)&av[0] = *(float4*)&As[k][tr * 8];
      *(float4*)&av[4] = *(float4*)&As[k][tr * 8 + 4];
      *(float4*)&bv[0] = *(float4*)&Bs[k][tc * 4];
      #pragma unroll
      for (int i = 0; i < 8; ++i)
        #pragma unroll
        for (int j = 0; j < 4; ++j)
          acc[i][j] = fmaf(av[i], bv[j], acc[i][j]);
    }
  }
  float4 bb = *(const float4*)&bias[tc * 4];
  #pragma unroll
  for (int i = 0; i < 8; ++i) {
    int grow = row0 + tr * 8 + i;
    if (grow < N_NODES) {
      float4 o0 = make_float4(acc[i][0] + bb.x, acc[i][1] + bb.y,
                              acc[i][2] + bb.z, acc[i][3] + bb.w);
      *(float4*)(C + (size_t)grow * D2 + tc * 4) = o0;
    }
  }
}

// ============================ per-node scores ============================
// sD[n,h] = sum_o Wh[n,h,o]*a[h,o]; sS[n,h] = sum_o Wh[n,h,o]*a[h,HID+o]
__global__ __launch_bounds__(256)
void k_scores1(const float* __restrict__ Wh, const float* __restrict__ a,
               float* __restrict__ sD, float* __restrict__ sS) {
  int wid = (blockIdx.x * blockDim.x + threadIdx.x) >> 6;
  int lane = threadIdx.x & 63;
  if (wid >= N_NODES) return;
  const float* row = Wh + (size_t)wid * D1;
  float pd[4], ps[4];
  #pragma unroll
  for (int h = 0; h < 4; ++h) {
    float w = row[h * 64 + lane];
    pd[h] = w * a[h * 128 + lane];
    ps[h] = w * a[h * 128 + 64 + lane];
  }
  #pragma unroll
  for (int o = 32; o; o >>= 1) {
    #pragma unroll
    for (int h = 0; h < 4; ++h) {
      pd[h] += __shfl_xor(pd[h], o);
      ps[h] += __shfl_xor(ps[h], o);
    }
  }
  if (lane == 0) {
    ((float4*)sD)[wid] = make_float4(pd[0], pd[1], pd[2], pd[3]);
    ((float4*)sS)[wid] = make_float4(ps[0], ps[1], ps[2], ps[3]);
  }
}

__global__ __launch_bounds__(256)
void k_scores2(const float* __restrict__ Wh, const float* __restrict__ a,
               float* __restrict__ sD, float* __restrict__ sS) {
  int wid = (blockIdx.x * blockDim.x + threadIdx.x) >> 6;
  int lane = threadIdx.x & 63;
  if (wid >= N_NODES) return;
  int h = lane >> 4, o = lane & 15;
  float w = Wh[(size_t)wid * D2 + lane];
  float pd = w * a[h * 32 + o];
  float ps = w * a[h * 32 + 16 + o];
  #pragma unroll
  for (int s = 8; s; s >>= 1) {
    pd += __shfl_xor(pd, s);
    ps += __shfl_xor(ps, s);
  }
  if (o == 0) {
    sD[wid * 4 + h] = pd;
    sS[wid * 4 + h] = ps;
  }
}

// ============================ layer-1 aggregate ============================
__device__ __forceinline__ float lrelu(float x) { return x > 0.f ? x : 0.2f * x; }
__device__ __forceinline__ float elu(float x)   { return x > 0.f ? x : expm1f(x); }

__global__ __launch_bounds__(256)
void k_agg1(const int* __restrict__ offs, const int* __restrict__ csrsrc,
            const float* __restrict__ sD, const float* __restrict__ sS,
            const float* __restrict__ ab,
            const float* __restrict__ Wh, float* __restrict__ h1out) {
  int wid = (blockIdx.x * blockDim.x + threadIdx.x) >> 6;
  int lane = threadIdx.x & 63;
  if (wid >= N_NODES) return;
  int beg = offs[wid], end = offs[wid + 1];
  float acc0 = 0.f, acc1 = 0.f, acc2 = 0.f, acc3 = 0.f;
  if (end > beg) {
    float4 dv = ((const float4*)sD)[wid];
    float db0 = dv.x + ab[0], db1 = dv.y + ab[1];
    float db2 = dv.z + ab[2], db3 = dv.w + ab[3];
    // pass 1: per-head max over incoming edges
    float m0 = -1e30f, m1 = -1e30f, m2 = -1e30f, m3 = -1e30f;
    for (int j = beg + lane; j < end; j += 64) {
      int s = csrsrc[j];
      float4 sv = ((const float4*)sS)[s];
      m0 = fmaxf(m0, lrelu(db0 + sv.x));
      m1 = fmaxf(m1, lrelu(db1 + sv.y));
      m2 = fmaxf(m2, lrelu(db2 + sv.z));
      m3 = fmaxf(m3, lrelu(db3 + sv.w));
    }
    #pragma unroll
    for (int o = 32; o; o >>= 1) {
      m0 = fmaxf(m0, __shfl_xor(m0, o));
      m1 = fmaxf(m1, __shfl_xor(m1, o));
      m2 = fmaxf(m2, __shfl_xor(m2, o));
      m3 = fmaxf(m3, __shfl_xor(m3, o));
    }
    // pass 2: unnormalized exp weights + aggregate (chunks of 64 edges)
    float z0 = 0.f, z1 = 0.f, z2 = 0.f, z3 = 0.f;
    for (int cbeg = beg; cbeg < end; cbeg += 64) {
      int j = cbeg + lane;
      int cnt = end - cbeg; if (cnt > 64) cnt = 64;
      float4 ex = make_float4(0.f, 0.f, 0.f, 0.f);
      int sid = 0;
      if (j < end) {
        sid = csrsrc[j];
        float4 sv = ((const float4*)sS)[sid];
        ex.x = expf(lrelu(db0 + sv.x) - m0);
        ex.y = expf(lrelu(db1 + sv.y) - m1);
        ex.z = expf(lrelu(db2 + sv.z) - m2);
        ex.w = expf(lrelu(db3 + sv.w) - m3);
        z0 += ex.x; z1 += ex.y; z2 += ex.z; z3 += ex.w;
      }
      for (int q = 0; q < cnt; ++q) {
        int s = __shfl(sid, q);
        float w0 = __shfl(ex.x, q);
        float w1 = __shfl(ex.y, q);
        float w2 = __shfl(ex.z, q);
        float w3 = __shfl(ex.w, q);
        const float* r = Wh + (size_t)s * D1;
        acc0 = fmaf(w0, r[lane],        acc0);
        acc1 = fmaf(w1, r[64 + lane],   acc1);
        acc2 = fmaf(w2, r[128 + lane],  acc2);
        acc3 = fmaf(w3, r[192 + lane],  acc3);
      }
    }
    #pragma unroll
    for (int o = 32; o; o >>= 1) {
      z0 += __shfl_xor(z0, o);
      z1 += __shfl_xor(z1, o);
      z2 += __shfl_xor(z2, o);
      z3 += __shfl_xor(z3, o);
    }
    acc0 /= z0; acc1 /= z1; acc2 /= z2; acc3 /= z3;
  }
  float* op = h1out + (size_t)wid * D1;
  op[lane]        = elu(acc0);
  op[64 + lane]   = elu(acc1);
  op[128 + lane]  = elu(acc2);
  op[192 + lane]  = elu(acc3);
}

// ============================ layer-2 aggregate + softmax + partial mean ====
__global__ __launch_bounds__(256)
void k_agg2(const int* __restrict__ offs, const int* __restrict__ csrsrc,
            const float* __restrict__ sD, const float* __restrict__ sS,
            const float* __restrict__ ab,
            const float* __restrict__ Wh, float* __restrict__ partials) {
  __shared__ float red[4][16];
  int widInBlk = threadIdx.x >> 6;
  int wid = blockIdx.x * 4 + widInBlk;
  int lane = threadIdx.x & 63;
  int h = lane >> 4, o = lane & 15;
  float p = 0.f;
  bool active = wid < N_NODES;
  if (active) {
    float val = 0.f;
    int beg = offs[wid], end = offs[wid + 1];
    if (end > beg) {
      float4 dv = ((const float4*)sD)[wid];
      float db0 = dv.x + ab[0], db1 = dv.y + ab[1];
      float db2 = dv.z + ab[2], db3 = dv.w + ab[3];
      float m0 = -1e30f, m1 = -1e30f, m2 = -1e30f, m3 = -1e30f;
      for (int j = beg + lane; j < end; j += 64) {
        int s = csrsrc[j];
        float4 sv = ((const float4*)sS)[s];
        m0 = fmaxf(m0, lrelu(db0 + sv.x));
        m1 = fmaxf(m1, lrelu(db1 + sv.y));
        m2 = fmaxf(m2, lrelu(db2 + sv.z));
        m3 = fmaxf(m3, lrelu(db3 + sv.w));
      }
      #pragma unroll
      for (int s = 32; s; s >>= 1) {
        m0 = fmaxf(m0, __shfl_xor(m0, s));
        m1 = fmaxf(m1, __shfl_xor(m1, s));
        m2 = fmaxf(m2, __shfl_xor(m2, s));
        m3 = fmaxf(m3, __shfl_xor(m3, s));
      }
      float acc = 0.f;
      float z0 = 0.f, z1 = 0.f, z2 = 0.f, z3 = 0.f;
      for (int cbeg = beg; cbeg < end; cbeg += 64) {
        int j = cbeg + lane;
        int cnt = end - cbeg; if (cnt > 64) cnt = 64;
        float4 ex = make_float4(0.f, 0.f, 0.f, 0.f);
        int sid = 0;
        if (j < end) {
          sid = csrsrc[j];
          float4 sv = ((const float4*)sS)[sid];
          ex.x = expf(lrelu(db0 + sv.x) - m0);
          ex.y = expf(lrelu(db1 + sv.y) - m1);
          ex.z = expf(lrelu(db2 + sv.z) - m2);
          ex.w = expf(lrelu(db3 + sv.w) - m3);
          z0 += ex.x; z1 += ex.y; z2 += ex.z; z3 += ex.w;
        }
        for (int q = 0; q < cnt; ++q) {
          int s = __shfl(sid, q);
          float w0 = __shfl(ex.x, q);
          float w1 = __shfl(ex.y, q);
          float w2 = __shfl(ex.z, q);
          float w3 = __shfl(ex.w, q);
          float w = (h == 0) ? w0 : (h == 1) ? w1 : (h == 2) ? w2 : w3;
          acc = fmaf(w, Wh[(size_t)s * D2 + lane], acc);
        }
      }
      #pragma unroll
      for (int s = 32; s; s >>= 1) {
        z0 += __shfl_xor(z0, s);
        z1 += __shfl_xor(z1, s);
        z2 += __shfl_xor(z2, s);
        z3 += __shfl_xor(z3, s);
      }
      float zh = (h == 0) ? z0 : (h == 1) ? z1 : (h == 2) ? z2 : z3;
      val = acc / zh;
    }
    // mean over heads: sum lanes {o, 16+o, 32+o, 48+o}
    val += __shfl_xor(val, 16);
    val += __shfl_xor(val, 32);
    val *= 0.25f;
    // softmax over 16 classes (within each 16-lane group; replicas identical)
    float mx = val;
    #pragma unroll
    for (int s = 8; s; s >>= 1) mx = fmaxf(mx, __shfl_xor(mx, s));
    float ev = expf(val - mx);
    float ssum = ev;
    #pragma unroll
    for (int s = 8; s; s >>= 1) ssum += __shfl_xor(ssum, s);
    p = ev / ssum;
  }
  if (lane < 16) red[widInBlk][lane] = active ? p : 0.f;
  __syncthreads();
  if (threadIdx.x < 16) {
    partials[(size_t)blockIdx.x * 16 + threadIdx.x] =
        red[0][threadIdx.x] + red[1][threadIdx.x] +
        red[2][threadIdx.x] + red[3][threadIdx.x];
  }
}

// ============================ final reduce + fc ============================
__global__ __launch_bounds__(256)
void k_final(const float* __restrict__ partials, int nblk,
             const float* __restrict__ fcw, const float* __restrict__ fcb,
             float* __restrict__ out) {
  __shared__ float red[256];
  __shared__ float hg[16];
  int t = threadIdx.x;
  int c = t & 15, r0 = t >> 4;
  float s = 0.f;
  for (int r = r0; r < nblk; r += 16) s += partials[(size_t)r * 16 + c];
  red[t] = s;
  __syncthreads();
  for (int st = 8; st; st >>= 1) {
    if (r0 < st) red[t] += red[t + st * 16];
    __syncthreads();
  }
  if (t < 16) hg[t] = red[t] * (1.0f / N_NODES);
  __syncthreads();
  if (t < 16) {
    float acc = fcb[t];
    #pragma unroll
    for (int k = 0; k < 16; ++k) acc += hg[k] * fcw[t * 16 + k];
    out[t] = acc;
  }
}

// ============================ launcher ============================
extern "C" void kernel_launch(void* const* d_in, const int* in_sizes, int n_in,
                              void* d_out, int out_size, void* d_ws, size_t ws_size,
                              hipStream_t stream) {
  const float* h   = (const float*)d_in[0];
  const int*   src = (const int*)  d_in[1];
  const int*   dst = (const int*)  d_in[2];
  const float* W1  = (const float*)d_in[3];
  const float* b1  = (const float*)d_in[4];
  const float* a1  = (const float*)d_in[5];
  const float* ab1 = (const float*)d_in[6];
  const float* W2  = (const float*)d_in[7];
  const float* b2  = (const float*)d_in[8];
  const float* a2  = (const float*)d_in[9];
  const float* ab2 = (const float*)d_in[10];
  const float* fcw = (const float*)d_in[11];
  const float* fcb = (const float*)d_in[12];
  float* out = (float*)d_out;

  char* ws = (char*)d_ws;
  size_t off = 0;
  auto alloc = [&](size_t bytes) -> char* {
    char* p = ws + off;
    off += (bytes + 255) & ~(size_t)255;
    return p;
  };
  // total ~246 MB of workspace
  float* Wh1 = (float*)alloc((size_t)N_NODES * D1 * 4);   // 102.4 MB
  float* h1  = (float*)alloc((size_t)N_NODES * D1 * 4);   // 102.4 MB
  float* Wh2 = (float*)alloc((size_t)N_NODES * D2 * 4);   // 25.6 MB
  float* sD1 = (float*)alloc((size_t)N_NODES * 4 * 4);
  float* sS1 = (float*)alloc((size_t)N_NODES * 4 * 4);
  float* sD2 = (float*)alloc((size_t)N_NODES * 4 * 4);
  float* sS2 = (float*)alloc((size_t)N_NODES * 4 * 4);
  int* counts = (int*)alloc((size_t)N_NODES * 4);
  int* offs   = (int*)alloc((size_t)(N_NODES + 1) * 4);
  int* cursor = (int*)alloc((size_t)N_NODES * 4);
  int* csrsrc = (int*)alloc((size_t)N_EDGES * 4);
  const int nblk_node = (N_NODES + 3) / 4;   // 25000 (exact)
  float* partials = (float*)alloc((size_t)nblk_node * 16 * 4);

  // --- CSR build (by dst) ---
  k_zero_i32<<<(N_NODES + 255) / 256, 256, 0, stream>>>(counts, N_NODES);
  k_count<<<(N_EDGES + 255) / 256, 256, 0, stream>>>(dst, counts);
  k_scan<<<1, 1024, 0, stream>>>(counts, offs, cursor);
  k_scatter<<<(N_EDGES + 255) / 256, 256, 0, stream>>>(src, dst, cursor, csrsrc);

  // --- layer 1 ---
  k_gemm1<<<dim3((N_NODES + 127) / 128, 2), 256, 0, stream>>>(h, W1, b1, Wh1);
  k_scores1<<<nblk_node, 256, 0, stream>>>(Wh1, a1, sD1, sS1);
  k_agg1<<<nblk_node, 256, 0, stream>>>(offs, csrsrc, sD1, sS1, ab1, Wh1, h1);

  // --- layer 2 ---
  k_gemm2<<<dim3((N_NODES + 127) / 128, 1), 256, 0, stream>>>(h1, W2, b2, Wh2);
  k_scores2<<<nblk_node, 256, 0, stream>>>(Wh2, a2, sD2, sS2);
  k_agg2<<<nblk_node, 256, 0, stream>>>(offs, csrsrc, sD2, sS2, ab2, Wh2, partials);

  // --- readout ---
  k_final<<<1, 256, 0, stream>>>(partials, nblk_node, fcw, fcb, out);
}

// Round 2
// 918.784 us; speedup vs baseline: 1.6250x; 1.6250x over previous
//
#include <hip/hip_runtime.h>
#include <math.h>

#define N_NODES  100000
#define N_EDGES  1600000
#define IN_F     128
#define HID      64
#define HEADS    4
#define NCLS     16
#define D1       (HEADS*HID)    // 256
#define D2       (HEADS*NCLS)   // 64

#define SCAN_CHUNK 1024
#define SCAN_NB    ((N_NODES + SCAN_CHUNK - 1) / SCAN_CHUNK)   // 98
#define N_NODES_PAD (SCAN_NB * SCAN_CHUNK)                     // 100352
#define RB1 128   // reduce-stage-1 blocks

// ============================ CSR build ============================
__global__ void k_zero_i32(int* __restrict__ p, int n) {
  int i = blockIdx.x * blockDim.x + threadIdx.x;
  if (i < n) p[i] = 0;
}

__global__ void k_count(const int* __restrict__ dst, int* __restrict__ counts) {
  int i = blockIdx.x * blockDim.x + threadIdx.x;
  if (i < N_EDGES) atomicAdd(&counts[dst[i]], 1);
}

// stage A: per-block (1024-node) totals.  grid = SCAN_NB, block = 256
__global__ __launch_bounds__(256)
void k_scanA(const int* __restrict__ counts, int* __restrict__ btot) {
  __shared__ int red[256];
  int t = threadIdx.x;
  const int4* cp = (const int4*)(counts + blockIdx.x * SCAN_CHUNK);
  int4 v = cp[t];                       // 256 * int4 = 1024 ints
  red[t] = v.x + v.y + v.z + v.w;
  __syncthreads();
  for (int s = 128; s; s >>= 1) {
    if (t < s) red[t] += red[t + s];
    __syncthreads();
  }
  if (t == 0) btot[blockIdx.x] = red[0];
}

// stage B: scan 98 block totals (1 tiny block)
__global__ __launch_bounds__(128)
void k_scanB(const int* __restrict__ btot, int* __restrict__ bbase,
             int* __restrict__ offs) {
  __shared__ int part[128];
  int t = threadIdx.x;
  part[t] = (t < SCAN_NB) ? btot[t] : 0;
  __syncthreads();
  for (int o = 1; o < 128; o <<= 1) {
    int v = (t >= o) ? part[t - o] : 0;
    __syncthreads();
    part[t] += v;
    __syncthreads();
  }
  if (t < SCAN_NB) bbase[t] = (t == 0) ? 0 : part[t - 1];
  if (t == 0) offs[N_NODES] = N_EDGES;
}

// stage C: per-block exclusive scan of 1024 counts + base; write offs & cursor
__global__ __launch_bounds__(256)
void k_scanC(const int* __restrict__ counts, const int* __restrict__ bbase,
             int* __restrict__ offs, int* __restrict__ cursor) {
  __shared__ int part[256];
  int t = threadIdx.x;
  int gbase = blockIdx.x * SCAN_CHUNK;
  const int4* cp = (const int4*)(counts + gbase);
  int4 v = cp[t];
  int tot = v.x + v.y + v.z + v.w;
  part[t] = tot;
  __syncthreads();
  for (int o = 1; o < 256; o <<= 1) {
    int q = (t >= o) ? part[t - o] : 0;
    __syncthreads();
    part[t] += q;
    __syncthreads();
  }
  int run = bbase[blockIdx.x] + part[t] - tot;   // exclusive base for this thread
  int i0 = gbase + t * 4;
  int o0 = run;
  int o1 = o0 + v.x;
  int o2 = o1 + v.y;
  int o3 = o2 + v.z;
  if (i0 + 0 < N_NODES) { offs[i0 + 0] = o0; cursor[i0 + 0] = o0; }
  if (i0 + 1 < N_NODES) { offs[i0 + 1] = o1; cursor[i0 + 1] = o1; }
  if (i0 + 2 < N_NODES) { offs[i0 + 2] = o2; cursor[i0 + 2] = o2; }
  if (i0 + 3 < N_NODES) { offs[i0 + 3] = o3; cursor[i0 + 3] = o3; }
}

__global__ void k_scatter(const int* __restrict__ src, const int* __restrict__ dst,
                          int* __restrict__ cursor, int* __restrict__ csrsrc) {
  int i = blockIdx.x * blockDim.x + threadIdx.x;
  if (i < N_EDGES) {
    int p = atomicAdd(&cursor[dst[i]], 1);
    csrsrc[p] = src[i];
  }
}

// ============================ GEMM 1 ============================
// C[N,256] = A[N,128] * B (+bias), B[f,c] = W1[(c>>6)*8192 + f*64 + (c&63)]
#define BK 32
__global__ __launch_bounds__(256)
void k_gemm1(const float* __restrict__ A, const float* __restrict__ W,
             const float* __restrict__ bias, float* __restrict__ C) {
  __shared__ float As[BK][128 + 4];
  __shared__ float Bs[BK][128 + 4];
  int t = threadIdx.x;
  int row0 = blockIdx.x * 128;
  int col0 = blockIdx.y * 128;
  int tr = t >> 4, tc = t & 15;
  float acc[8][8] = {};
  int ar = t >> 1;             // 0..127
  int ac = (t & 1) * 16;       // 0 or 16

  for (int kk = 0; kk < IN_F; kk += BK) {
    __syncthreads();
    {
      int grow = row0 + ar;
      float av[16];
      if (grow < N_NODES) {
        const float4* ap = (const float4*)(A + (size_t)grow * IN_F + kk + ac);
        *(float4*)&av[0]  = ap[0];
        *(float4*)&av[4]  = ap[1];
        *(float4*)&av[8]  = ap[2];
        *(float4*)&av[12] = ap[3];
      } else {
        #pragma unroll
        for (int u = 0; u < 16; ++u) av[u] = 0.f;
      }
      #pragma unroll
      for (int u = 0; u < 16; ++u) As[ac + u][ar] = av[u];
    }
    #pragma unroll
    for (int j = 0; j < 4; ++j) {
      int s = t + j * 256;
      int f = s >> 5;           // 0..31
      int c = (s & 31) * 4;     // 0..124
      int gc = col0 + c;
      const float* wp = W + ((gc >> 6) << 13) + ((size_t)(kk + f) << 6) + (gc & 63);
      *(float4*)&Bs[f][c] = *(const float4*)wp;
    }
    __syncthreads();
    for (int k = 0; k < BK; ++k) {
      float av[8], bv[8];
      *(float4*)&av[0] = *(float4*)&As[k][tr * 8];
      *(float4*)&av[4] = *(float4*)&As[k][tr * 8 + 4];
      *(float4*)&bv[0] = *(float4*)&Bs[k][tc * 8];
      *(float4*)&bv[4] = *(float4*)&Bs[k][tc * 8 + 4];
      #pragma unroll
      for (int i = 0; i < 8; ++i)
        #pragma unroll
        for (int j = 0; j < 8; ++j)
          acc[i][j] = fmaf(av[i], bv[j], acc[i][j]);
    }
  }
  float4 bb0 = *(const float4*)&bias[col0 + tc * 8];
  float4 bb1 = *(const float4*)&bias[col0 + tc * 8 + 4];
  #pragma unroll
  for (int i = 0; i < 8; ++i) {
    int grow = row0 + tr * 8 + i;
    if (grow < N_NODES) {
      float4 o0 = make_float4(acc[i][0] + bb0.x, acc[i][1] + bb0.y,
                              acc[i][2] + bb0.z, acc[i][3] + bb0.w);
      float4 o1 = make_float4(acc[i][4] + bb1.x, acc[i][5] + bb1.y,
                              acc[i][6] + bb1.z, acc[i][7] + bb1.w);
      float4* cp = (float4*)(C + (size_t)grow * D1 + col0 + tc * 8);
      cp[0] = o0; cp[1] = o1;
    }
  }
}

// ============================ GEMM 2 ============================
__global__ __launch_bounds__(256)
void k_gemm2(const float* __restrict__ A, const float* __restrict__ W,
             const float* __restrict__ bias, float* __restrict__ C) {
  __shared__ float As[BK][128 + 4];
  __shared__ float Bs[BK][64 + 4];
  int t = threadIdx.x;
  int row0 = blockIdx.x * 128;
  int tr = t >> 4, tc = t & 15;
  float acc[8][4] = {};
  int ar = t >> 1;
  int ac = (t & 1) * 16;

  for (int kk = 0; kk < D1; kk += BK) {
    __syncthreads();
    {
      int grow = row0 + ar;
      float av[16];
      if (grow < N_NODES) {
        const float4* ap = (const float4*)(A + (size_t)grow * D1 + kk + ac);
        *(float4*)&av[0]  = ap[0];
        *(float4*)&av[4]  = ap[1];
        *(float4*)&av[8]  = ap[2];
        *(float4*)&av[12] = ap[3];
      } else {
        #pragma unroll
        for (int u = 0; u < 16; ++u) av[u] = 0.f;
      }
      #pragma unroll
      for (int u = 0; u < 16; ++u) As[ac + u][ar] = av[u];
    }
    #pragma unroll
    for (int j = 0; j < 2; ++j) {
      int s = t + j * 256;
      int f = s >> 4;
      int c = (s & 15) * 4;
      const float* wp = W + ((c >> 4) << 12) + ((size_t)(kk + f) << 4) + (c & 15);
      *(float4*)&Bs[f][c] = *(const float4*)wp;
    }
    __syncthreads();
    for (int k = 0; k < BK; ++k) {
      float av[8], bv[4];
      *(float4*)&av[0] = *(float4*)&As[k][tr * 8];
      *(float4*)&av[4] = *(float4*)&As[k][tr * 8 + 4];
      *(float4*)&bv[0] = *(float4*)&Bs[k][tc * 4];
      #pragma unroll
      for (int i = 0; i < 8; ++i)
        #pragma unroll
        for (int j = 0; j < 4; ++j)
          acc[i][j] = fmaf(av[i], bv[j], acc[i][j]);
    }
  }
  float4 bb = *(const float4*)&bias[tc * 4];
  #pragma unroll
  for (int i = 0; i < 8; ++i) {
    int grow = row0 + tr * 8 + i;
    if (grow < N_NODES) {
      float4 o0 = make_float4(acc[i][0] + bb.x, acc[i][1] + bb.y,
                              acc[i][2] + bb.z, acc[i][3] + bb.w);
      *(float4*)(C + (size_t)grow * D2 + tc * 4) = o0;
    }
  }
}

// ============================ per-node scores ============================
__global__ __launch_bounds__(256)
void k_scores1(const float* __restrict__ Wh, const float* __restrict__ a,
               float* __restrict__ sD, float* __restrict__ sS) {
  int wid = (blockIdx.x * blockDim.x + threadIdx.x) >> 6;
  int lane = threadIdx.x & 63;
  if (wid >= N_NODES) return;
  const float* row = Wh + (size_t)wid * D1;
  float pd[4], ps[4];
  #pragma unroll
  for (int h = 0; h < 4; ++h) {
    float w = row[h * 64 + lane];
    pd[h] = w * a[h * 128 + lane];
    ps[h] = w * a[h * 128 + 64 + lane];
  }
  #pragma unroll
  for (int o = 32; o; o >>= 1) {
    #pragma unroll
    for (int h = 0; h < 4; ++h) {
      pd[h] += __shfl_xor(pd[h], o);
      ps[h] += __shfl_xor(ps[h], o);
    }
  }
  if (lane == 0) {
    ((float4*)sD)[wid] = make_float4(pd[0], pd[1], pd[2], pd[3]);
    ((float4*)sS)[wid] = make_float4(ps[0], ps[1], ps[2], ps[3]);
  }
}

__global__ __launch_bounds__(256)
void k_scores2(const float* __restrict__ Wh, const float* __restrict__ a,
               float* __restrict__ sD, float* __restrict__ sS) {
  int wid = (blockIdx.x * blockDim.x + threadIdx.x) >> 6;
  int lane = threadIdx.x & 63;
  if (wid >= N_NODES) return;
  int h = lane >> 4, o = lane & 15;
  float w = Wh[(size_t)wid * D2 + lane];
  float pd = w * a[h * 32 + o];
  float ps = w * a[h * 32 + 16 + o];
  #pragma unroll
  for (int s = 8; s; s >>= 1) {
    pd += __shfl_xor(pd, s);
    ps += __shfl_xor(ps, s);
  }
  if (o == 0) {
    sD[wid * 4 + h] = pd;
    sS[wid * 4 + h] = ps;
  }
}

// ============================ layer-1 aggregate ============================
__device__ __forceinline__ float lrelu(float x) { return x > 0.f ? x : 0.2f * x; }
__device__ __forceinline__ float elu(float x)   { return x > 0.f ? x : expm1f(x); }

__global__ __launch_bounds__(256)
void k_agg1(const int* __restrict__ offs, const int* __restrict__ csrsrc,
            const float* __restrict__ sD, const float* __restrict__ sS,
            const float* __restrict__ ab,
            const float* __restrict__ Wh, float* __restrict__ h1out) {
  int wid = (blockIdx.x * blockDim.x + threadIdx.x) >> 6;
  int lane = threadIdx.x & 63;
  if (wid >= N_NODES) return;
  int beg = offs[wid], end = offs[wid + 1];
  float acc0 = 0.f, acc1 = 0.f, acc2 = 0.f, acc3 = 0.f;
  if (end > beg) {
    float4 dv = ((const float4*)sD)[wid];
    float db0 = dv.x + ab[0], db1 = dv.y + ab[1];
    float db2 = dv.z + ab[2], db3 = dv.w + ab[3];
    float m0 = -1e30f, m1 = -1e30f, m2 = -1e30f, m3 = -1e30f;
    for (int j = beg + lane; j < end; j += 64) {
      int s = csrsrc[j];
      float4 sv = ((const float4*)sS)[s];
      m0 = fmaxf(m0, lrelu(db0 + sv.x));
      m1 = fmaxf(m1, lrelu(db1 + sv.y));
      m2 = fmaxf(m2, lrelu(db2 + sv.z));
      m3 = fmaxf(m3, lrelu(db3 + sv.w));
    }
    #pragma unroll
    for (int o = 32; o; o >>= 1) {
      m0 = fmaxf(m0, __shfl_xor(m0, o));
      m1 = fmaxf(m1, __shfl_xor(m1, o));
      m2 = fmaxf(m2, __shfl_xor(m2, o));
      m3 = fmaxf(m3, __shfl_xor(m3, o));
    }
    float z0 = 0.f, z1 = 0.f, z2 = 0.f, z3 = 0.f;
    for (int cbeg = beg; cbeg < end; cbeg += 64) {
      int j = cbeg + lane;
      int cnt = end - cbeg; if (cnt > 64) cnt = 64;
      float4 ex = make_float4(0.f, 0.f, 0.f, 0.f);
      int sid = 0;
      if (j < end) {
        sid = csrsrc[j];
        float4 sv = ((const float4*)sS)[sid];
        ex.x = expf(lrelu(db0 + sv.x) - m0);
        ex.y = expf(lrelu(db1 + sv.y) - m1);
        ex.z = expf(lrelu(db2 + sv.z) - m2);
        ex.w = expf(lrelu(db3 + sv.w) - m3);
        z0 += ex.x; z1 += ex.y; z2 += ex.z; z3 += ex.w;
      }
      for (int q = 0; q < cnt; ++q) {
        int s = __shfl(sid, q);
        float w0 = __shfl(ex.x, q);
        float w1 = __shfl(ex.y, q);
        float w2 = __shfl(ex.z, q);
        float w3 = __shfl(ex.w, q);
        const float* r = Wh + (size_t)s * D1;
        acc0 = fmaf(w0, r[lane],        acc0);
        acc1 = fmaf(w1, r[64 + lane],   acc1);
        acc2 = fmaf(w2, r[128 + lane],  acc2);
        acc3 = fmaf(w3, r[192 + lane],  acc3);
      }
    }
    #pragma unroll
    for (int o = 32; o; o >>= 1) {
      z0 += __shfl_xor(z0, o);
      z1 += __shfl_xor(z1, o);
      z2 += __shfl_xor(z2, o);
      z3 += __shfl_xor(z3, o);
    }
    acc0 /= z0; acc1 /= z1; acc2 /= z2; acc3 /= z3;
  }
  float* op = h1out + (size_t)wid * D1;
  op[lane]        = elu(acc0);
  op[64 + lane]   = elu(acc1);
  op[128 + lane]  = elu(acc2);
  op[192 + lane]  = elu(acc3);
}

// ============================ layer-2 aggregate + softmax + partial mean ====
__global__ __launch_bounds__(256)
void k_agg2(const int* __restrict__ offs, const int* __restrict__ csrsrc,
            const float* __restrict__ sD, const float* __restrict__ sS,
            const float* __restrict__ ab,
            const float* __restrict__ Wh, float* __restrict__ partials) {
  __shared__ float red[4][16];
  int widInBlk = threadIdx.x >> 6;
  int wid = blockIdx.x * 4 + widInBlk;
  int lane = threadIdx.x & 63;
  int h = lane >> 4, o = lane & 15;
  float p = 0.f;
  bool active = wid < N_NODES;
  if (active) {
    float val = 0.f;
    int beg = offs[wid], end = offs[wid + 1];
    if (end > beg) {
      float4 dv = ((const float4*)sD)[wid];
      float db0 = dv.x + ab[0], db1 = dv.y + ab[1];
      float db2 = dv.z + ab[2], db3 = dv.w + ab[3];
      float m0 = -1e30f, m1 = -1e30f, m2 = -1e30f, m3 = -1e30f;
      for (int j = beg + lane; j < end; j += 64) {
        int s = csrsrc[j];
        float4 sv = ((const float4*)sS)[s];
        m0 = fmaxf(m0, lrelu(db0 + sv.x));
        m1 = fmaxf(m1, lrelu(db1 + sv.y));
        m2 = fmaxf(m2, lrelu(db2 + sv.z));
        m3 = fmaxf(m3, lrelu(db3 + sv.w));
      }
      #pragma unroll
      for (int s = 32; s; s >>= 1) {
        m0 = fmaxf(m0, __shfl_xor(m0, s));
        m1 = fmaxf(m1, __shfl_xor(m1, s));
        m2 = fmaxf(m2, __shfl_xor(m2, s));
        m3 = fmaxf(m3, __shfl_xor(m3, s));
      }
      float acc = 0.f;
      float z0 = 0.f, z1 = 0.f, z2 = 0.f, z3 = 0.f;
      for (int cbeg = beg; cbeg < end; cbeg += 64) {
        int j = cbeg + lane;
        int cnt = end - cbeg; if (cnt > 64) cnt = 64;
        float4 ex = make_float4(0.f, 0.f, 0.f, 0.f);
        int sid = 0;
        if (j < end) {
          sid = csrsrc[j];
          float4 sv = ((const float4*)sS)[sid];
          ex.x = expf(lrelu(db0 + sv.x) - m0);
          ex.y = expf(lrelu(db1 + sv.y) - m1);
          ex.z = expf(lrelu(db2 + sv.z) - m2);
          ex.w = expf(lrelu(db3 + sv.w) - m3);
          z0 += ex.x; z1 += ex.y; z2 += ex.z; z3 += ex.w;
        }
        for (int q = 0; q < cnt; ++q) {
          int s = __shfl(sid, q);
          float w0 = __shfl(ex.x, q);
          float w1 = __shfl(ex.y, q);
          float w2 = __shfl(ex.z, q);
          float w3 = __shfl(ex.w, q);
          float w = (h == 0) ? w0 : (h == 1) ? w1 : (h == 2) ? w2 : w3;
          acc = fmaf(w, Wh[(size_t)s * D2 + lane], acc);
        }
      }
      #pragma unroll
      for (int s = 32; s; s >>= 1) {
        z0 += __shfl_xor(z0, s);
        z1 += __shfl_xor(z1, s);
        z2 += __shfl_xor(z2, s);
        z3 += __shfl_xor(z3, s);
      }
      float zh = (h == 0) ? z0 : (h == 1) ? z1 : (h == 2) ? z2 : z3;
      val = acc / zh;
    }
    val += __shfl_xor(val, 16);
    val += __shfl_xor(val, 32);
    val *= 0.25f;
    float mx = val;
    #pragma unroll
    for (int s = 8; s; s >>= 1) mx = fmaxf(mx, __shfl_xor(mx, s));
    float ev = expf(val - mx);
    float ssum = ev;
    #pragma unroll
    for (int s = 8; s; s >>= 1) ssum += __shfl_xor(ssum, s);
    p = ev / ssum;
  }
  if (lane < 16) red[widInBlk][lane] = active ? p : 0.f;
  __syncthreads();
  if (threadIdx.x < 16) {
    partials[(size_t)blockIdx.x * 16 + threadIdx.x] =
        red[0][threadIdx.x] + red[1][threadIdx.x] +
        red[2][threadIdx.x] + red[3][threadIdx.x];
  }
}

// ============== hierarchical final reduce: 25000 -> 128 -> fc ==============
__global__ __launch_bounds__(256)
void k_reduce1(const float* __restrict__ partials, int nrows,
               float* __restrict__ out) {  // out: RB1 x 16
  __shared__ float red[16][17];
  int t = threadIdx.x;
  int c = t & 15, rl = t >> 4;           // 16 parallel row-lanes
  int per = (nrows + RB1 - 1) / RB1;
  int rbeg = blockIdx.x * per;
  int rend = rbeg + per; if (rend > nrows) rend = nrows;
  float s = 0.f;
  for (int r = rbeg + rl; r < rend; r += 16) s += partials[(size_t)r * 16 + c];
  red[rl][c] = s;
  __syncthreads();
  for (int st = 8; st; st >>= 1) {
    if (rl < st) red[rl][c] += red[rl + st][c];
    __syncthreads();
  }
  if (t < 16) out[(size_t)blockIdx.x * 16 + t] = red[0][t];
}

__global__ __launch_bounds__(256)
void k_final(const float* __restrict__ partials,   // RB1 x 16
             const float* __restrict__ fcw, const float* __restrict__ fcb,
             float* __restrict__ out) {
  __shared__ float red[16][17];
  __shared__ float hg[16];
  int t = threadIdx.x;
  int c = t & 15, rl = t >> 4;
  float s = 0.f;
  for (int r = rl; r < RB1; r += 16) s += partials[(size_t)r * 16 + c];
  red[rl][c] = s;
  __syncthreads();
  for (int st = 8; st; st >>= 1) {
    if (rl < st) red[rl][c] += red[rl + st][c];
    __syncthreads();
  }
  if (t < 16) hg[t] = red[0][t] * (1.0f / N_NODES);
  __syncthreads();
  if (t < 16) {
    float acc = fcb[t];
    #pragma unroll
    for (int k = 0; k < 16; ++k) acc += hg[k] * fcw[t * 16 + k];
    out[t] = acc;
  }
}

// ============================ launcher ============================
extern "C" void kernel_launch(void* const* d_in, const int* in_sizes, int n_in,
                              void* d_out, int out_size, void* d_ws, size_t ws_size,
                              hipStream_t stream) {
  const float* h   = (const float*)d_in[0];
  const int*   src = (const int*)  d_in[1];
  const int*   dst = (const int*)  d_in[2];
  const float* W1  = (const float*)d_in[3];
  const float* b1  = (const float*)d_in[4];
  const float* a1  = (const float*)d_in[5];
  const float* ab1 = (const float*)d_in[6];
  const float* W2  = (const float*)d_in[7];
  const float* b2  = (const float*)d_in[8];
  const float* a2  = (const float*)d_in[9];
  const float* ab2 = (const float*)d_in[10];
  const float* fcw = (const float*)d_in[11];
  const float* fcb = (const float*)d_in[12];
  float* out = (float*)d_out;

  char* ws = (char*)d_ws;
  size_t off = 0;
  auto alloc = [&](size_t bytes) -> char* {
    char* p = ws + off;
    off += (bytes + 255) & ~(size_t)255;
    return p;
  };
  float* Wh1 = (float*)alloc((size_t)N_NODES * D1 * 4);   // 102.4 MB
  float* h1  = (float*)alloc((size_t)N_NODES * D1 * 4);   // 102.4 MB
  float* Wh2 = (float*)alloc((size_t)N_NODES * D2 * 4);   // 25.6 MB
  float* sD1 = (float*)alloc((size_t)N_NODES * 4 * 4);
  float* sS1 = (float*)alloc((size_t)N_NODES * 4 * 4);
  float* sD2 = (float*)alloc((size_t)N_NODES * 4 * 4);
  float* sS2 = (float*)alloc((size_t)N_NODES * 4 * 4);
  int* counts = (int*)alloc((size_t)N_NODES_PAD * 4);     // padded for int4 loads
  int* offs   = (int*)alloc((size_t)(N_NODES + 1) * 4);
  int* cursor = (int*)alloc((size_t)N_NODES * 4);
  int* csrsrc = (int*)alloc((size_t)N_EDGES * 4);
  int* btot   = (int*)alloc((size_t)SCAN_NB * 4);
  int* bbase  = (int*)alloc((size_t)SCAN_NB * 4);
  const int nblk_node = (N_NODES + 3) / 4;   // 25000
  float* partials  = (float*)alloc((size_t)nblk_node * 16 * 4);
  float* partials2 = (float*)alloc((size_t)RB1 * 16 * 4);

  // --- CSR build (by dst) ---
  k_zero_i32<<<(N_NODES_PAD + 255) / 256, 256, 0, stream>>>(counts, N_NODES_PAD);
  k_count<<<(N_EDGES + 255) / 256, 256, 0, stream>>>(dst, counts);
  k_scanA<<<SCAN_NB, 256, 0, stream>>>(counts, btot);
  k_scanB<<<1, 128, 0, stream>>>(btot, bbase, offs);
  k_scanC<<<SCAN_NB, 256, 0, stream>>>(counts, bbase, offs, cursor);
  k_scatter<<<(N_EDGES + 255) / 256, 256, 0, stream>>>(src, dst, cursor, csrsrc);

  // --- layer 1 ---
  k_gemm1<<<dim3((N_NODES + 127) / 128, 2), 256, 0, stream>>>(h, W1, b1, Wh1);
  k_scores1<<<nblk_node, 256, 0, stream>>>(Wh1, a1, sD1, sS1);
  k_agg1<<<nblk_node, 256, 0, stream>>>(offs, csrsrc, sD1, sS1, ab1, Wh1, h1);

  // --- layer 2 ---
  k_gemm2<<<dim3((N_NODES + 127) / 128, 1), 256, 0, stream>>>(h1, W2, b2, Wh2);
  k_scores2<<<nblk_node, 256, 0, stream>>>(Wh2, a2, sD2, sS2);
  k_agg2<<<nblk_node, 256, 0, stream>>>(offs, csrsrc, sD2, sS2, ab2, Wh2, partials);

  // --- readout ---
  k_reduce1<<<RB1, 256, 0, stream>>>(partials, nblk_node, partials2);
  k_final<<<1, 256, 0, stream>>>(partials2, fcw, fcb, out);
}

// Round 3
// 793.108 us; speedup vs baseline: 1.8825x; 1.1585x over previous
//
#include <hip/hip_runtime.h>
#include <math.h>

#define N_NODES  100000
#define N_EDGES  1600000
#define IN_F     128
#define HID      64
#define HEADS    4
#define NCLS     16
#define D1       (HEADS*HID)    // 256
#define D2       (HEADS*NCLS)   // 64

#define SCAN_CHUNK 1024
#define SCAN_NB    ((N_NODES + SCAN_CHUNK - 1) / SCAN_CHUNK)   // 98
#define N_NODES_PAD (SCAN_NB * SCAN_CHUNK)                     // 100352
#define RB1 128   // reduce-stage-1 blocks

// bf16 helpers (RNE)
__device__ __forceinline__ unsigned bf16rne(float x) {
  unsigned u = __float_as_uint(x);
  return (u + 0x7fffu + ((u >> 16) & 1u)) >> 16;
}
__device__ __forceinline__ unsigned packbf2(float lo, float hi) {
  return bf16rne(lo) | (bf16rne(hi) << 16);
}
__device__ __forceinline__ float bflo(unsigned p) { return __uint_as_float(p << 16); }
__device__ __forceinline__ float bfhi(unsigned p) { return __uint_as_float(p & 0xffff0000u); }

// ============================ CSR build ============================
__global__ void k_zero_i32(int* __restrict__ p, int n) {
  int i = blockIdx.x * blockDim.x + threadIdx.x;
  if (i < n) p[i] = 0;
}

__global__ void k_count(const int* __restrict__ dst, int* __restrict__ counts) {
  int i = blockIdx.x * blockDim.x + threadIdx.x;
  if (i < N_EDGES) atomicAdd(&counts[dst[i]], 1);
}

__global__ __launch_bounds__(256)
void k_scanA(const int* __restrict__ counts, int* __restrict__ btot) {
  __shared__ int red[256];
  int t = threadIdx.x;
  const int4* cp = (const int4*)(counts + blockIdx.x * SCAN_CHUNK);
  int4 v = cp[t];
  red[t] = v.x + v.y + v.z + v.w;
  __syncthreads();
  for (int s = 128; s; s >>= 1) {
    if (t < s) red[t] += red[t + s];
    __syncthreads();
  }
  if (t == 0) btot[blockIdx.x] = red[0];
}

__global__ __launch_bounds__(128)
void k_scanB(const int* __restrict__ btot, int* __restrict__ bbase,
             int* __restrict__ offs) {
  __shared__ int part[128];
  int t = threadIdx.x;
  part[t] = (t < SCAN_NB) ? btot[t] : 0;
  __syncthreads();
  for (int o = 1; o < 128; o <<= 1) {
    int v = (t >= o) ? part[t - o] : 0;
    __syncthreads();
    part[t] += v;
    __syncthreads();
  }
  if (t < SCAN_NB) bbase[t] = (t == 0) ? 0 : part[t - 1];
  if (t == 0) offs[N_NODES] = N_EDGES;
}

__global__ __launch_bounds__(256)
void k_scanC(const int* __restrict__ counts, const int* __restrict__ bbase,
             int* __restrict__ offs, int* __restrict__ cursor) {
  __shared__ int part[256];
  int t = threadIdx.x;
  int gbase = blockIdx.x * SCAN_CHUNK;
  const int4* cp = (const int4*)(counts + gbase);
  int4 v = cp[t];
  int tot = v.x + v.y + v.z + v.w;
  part[t] = tot;
  __syncthreads();
  for (int o = 1; o < 256; o <<= 1) {
    int q = (t >= o) ? part[t - o] : 0;
    __syncthreads();
    part[t] += q;
    __syncthreads();
  }
  int run = bbase[blockIdx.x] + part[t] - tot;
  int i0 = gbase + t * 4;
  int o0 = run;
  int o1 = o0 + v.x;
  int o2 = o1 + v.y;
  int o3 = o2 + v.z;
  if (i0 + 0 < N_NODES) { offs[i0 + 0] = o0; cursor[i0 + 0] = o0; }
  if (i0 + 1 < N_NODES) { offs[i0 + 1] = o1; cursor[i0 + 1] = o1; }
  if (i0 + 2 < N_NODES) { offs[i0 + 2] = o2; cursor[i0 + 2] = o2; }
  if (i0 + 3 < N_NODES) { offs[i0 + 3] = o3; cursor[i0 + 3] = o3; }
}

__global__ void k_scatter(const int* __restrict__ src, const int* __restrict__ dst,
                          int* __restrict__ cursor, int* __restrict__ csrsrc) {
  int i = blockIdx.x * blockDim.x + threadIdx.x;
  if (i < N_EDGES) {
    int p = atomicAdd(&cursor[dst[i]], 1);
    csrsrc[p] = src[i];
  }
}

// ============================ GEMM 1 ============================
// Whb[N,256] (bf16) = A[N,128] * B (+bias); B[f,c] = W1[(c>>6)*8192 + f*64 + (c&63)]
#define BK 32
__global__ __launch_bounds__(256)
void k_gemm1(const float* __restrict__ A, const float* __restrict__ W,
             const float* __restrict__ bias, unsigned short* __restrict__ Whb) {
  __shared__ float As[BK][128 + 4];
  __shared__ float Bs[BK][128 + 4];
  int t = threadIdx.x;
  int row0 = blockIdx.x * 128;
  int col0 = blockIdx.y * 128;
  int tr = t >> 4, tc = t & 15;
  float acc[8][8] = {};
  int ar = t >> 1;
  int ac = (t & 1) * 16;

  for (int kk = 0; kk < IN_F; kk += BK) {
    __syncthreads();
    {
      int grow = row0 + ar;
      float av[16];
      if (grow < N_NODES) {
        const float4* ap = (const float4*)(A + (size_t)grow * IN_F + kk + ac);
        *(float4*)&av[0]  = ap[0];
        *(float4*)&av[4]  = ap[1];
        *(float4*)&av[8]  = ap[2];
        *(float4*)&av[12] = ap[3];
      } else {
        #pragma unroll
        for (int u = 0; u < 16; ++u) av[u] = 0.f;
      }
      #pragma unroll
      for (int u = 0; u < 16; ++u) As[ac + u][ar] = av[u];
    }
    #pragma unroll
    for (int j = 0; j < 4; ++j) {
      int s = t + j * 256;
      int f = s >> 5;
      int c = (s & 31) * 4;
      int gc = col0 + c;
      const float* wp = W + ((gc >> 6) << 13) + ((size_t)(kk + f) << 6) + (gc & 63);
      *(float4*)&Bs[f][c] = *(const float4*)wp;
    }
    __syncthreads();
    for (int k = 0; k < BK; ++k) {
      float av[8], bv[8];
      *(float4*)&av[0] = *(float4*)&As[k][tr * 8];
      *(float4*)&av[4] = *(float4*)&As[k][tr * 8 + 4];
      *(float4*)&bv[0] = *(float4*)&Bs[k][tc * 8];
      *(float4*)&bv[4] = *(float4*)&Bs[k][tc * 8 + 4];
      #pragma unroll
      for (int i = 0; i < 8; ++i)
        #pragma unroll
        for (int j = 0; j < 8; ++j)
          acc[i][j] = fmaf(av[i], bv[j], acc[i][j]);
    }
  }
  float4 bb0 = *(const float4*)&bias[col0 + tc * 8];
  float4 bb1 = *(const float4*)&bias[col0 + tc * 8 + 4];
  #pragma unroll
  for (int i = 0; i < 8; ++i) {
    int grow = row0 + tr * 8 + i;
    if (grow < N_NODES) {
      uint4 o;
      o.x = packbf2(acc[i][0] + bb0.x, acc[i][1] + bb0.y);
      o.y = packbf2(acc[i][2] + bb0.z, acc[i][3] + bb0.w);
      o.z = packbf2(acc[i][4] + bb1.x, acc[i][5] + bb1.y);
      o.w = packbf2(acc[i][6] + bb1.z, acc[i][7] + bb1.w);
      *(uint4*)(Whb + (size_t)grow * D1 + col0 + tc * 8) = o;
    }
  }
}

// ============================ GEMM 2 ============================
// Whb2[N,64] (bf16) = A[N,256] * B (+bias); B[f,c] = W2[(c>>4)*4096 + f*16 + (c&15)]
__global__ __launch_bounds__(256)
void k_gemm2(const float* __restrict__ A, const float* __restrict__ W,
             const float* __restrict__ bias, unsigned short* __restrict__ Whb2) {
  __shared__ float As[BK][128 + 4];
  __shared__ float Bs[BK][64 + 4];
  int t = threadIdx.x;
  int row0 = blockIdx.x * 128;
  int tr = t >> 4, tc = t & 15;
  float acc[8][4] = {};
  int ar = t >> 1;
  int ac = (t & 1) * 16;

  for (int kk = 0; kk < D1; kk += BK) {
    __syncthreads();
    {
      int grow = row0 + ar;
      float av[16];
      if (grow < N_NODES) {
        const float4* ap = (const float4*)(A + (size_t)grow * D1 + kk + ac);
        *(float4*)&av[0]  = ap[0];
        *(float4*)&av[4]  = ap[1];
        *(float4*)&av[8]  = ap[2];
        *(float4*)&av[12] = ap[3];
      } else {
        #pragma unroll
        for (int u = 0; u < 16; ++u) av[u] = 0.f;
      }
      #pragma unroll
      for (int u = 0; u < 16; ++u) As[ac + u][ar] = av[u];
    }
    #pragma unroll
    for (int j = 0; j < 2; ++j) {
      int s = t + j * 256;
      int f = s >> 4;
      int c = (s & 15) * 4;
      const float* wp = W + ((c >> 4) << 12) + ((size_t)(kk + f) << 4) + (c & 15);
      *(float4*)&Bs[f][c] = *(const float4*)wp;
    }
    __syncthreads();
    for (int k = 0; k < BK; ++k) {
      float av[8], bv[4];
      *(float4*)&av[0] = *(float4*)&As[k][tr * 8];
      *(float4*)&av[4] = *(float4*)&As[k][tr * 8 + 4];
      *(float4*)&bv[0] = *(float4*)&Bs[k][tc * 4];
      #pragma unroll
      for (int i = 0; i < 8; ++i)
        #pragma unroll
        for (int j = 0; j < 4; ++j)
          acc[i][j] = fmaf(av[i], bv[j], acc[i][j]);
    }
  }
  float4 bb = *(const float4*)&bias[tc * 4];
  #pragma unroll
  for (int i = 0; i < 8; ++i) {
    int grow = row0 + tr * 8 + i;
    if (grow < N_NODES) {
      uint2 o;
      o.x = packbf2(acc[i][0] + bb.x, acc[i][1] + bb.y);
      o.y = packbf2(acc[i][2] + bb.z, acc[i][3] + bb.w);
      *(uint2*)(Whb2 + (size_t)grow * D2 + tc * 4) = o;
    }
  }
}

// ============================ per-node scores ============================
// lane covers feats 4*lane..4*lane+3, head = lane>>4
__global__ __launch_bounds__(256)
void k_scores1(const unsigned short* __restrict__ Whb, const float* __restrict__ a,
               float* __restrict__ sD, float* __restrict__ sS) {
  int wid = (blockIdx.x * blockDim.x + threadIdx.x) >> 6;
  int lane = threadIdx.x & 63;
  if (wid >= N_NODES) return;
  int h = lane >> 4;
  uint2 p = *(const uint2*)(Whb + (size_t)wid * D1 + lane * 4);
  float f0 = bflo(p.x), f1 = bfhi(p.x), f2 = bflo(p.y), f3 = bfhi(p.y);
  int o0 = (lane & 15) * 4;
  const float* ah = a + h * 128;
  float pd = f0 * ah[o0] + f1 * ah[o0 + 1] + f2 * ah[o0 + 2] + f3 * ah[o0 + 3];
  float ps = f0 * ah[64 + o0] + f1 * ah[64 + o0 + 1] + f2 * ah[64 + o0 + 2] + f3 * ah[64 + o0 + 3];
  #pragma unroll
  for (int s = 8; s; s >>= 1) {
    pd += __shfl_xor(pd, s);
    ps += __shfl_xor(ps, s);
  }
  float4 dv = make_float4(__shfl(pd, 0), __shfl(pd, 16), __shfl(pd, 32), __shfl(pd, 48));
  float4 sv = make_float4(__shfl(ps, 0), __shfl(ps, 16), __shfl(ps, 32), __shfl(ps, 48));
  if (lane == 0) {
    ((float4*)sD)[wid] = dv;
    ((float4*)sS)[wid] = sv;
  }
}

__global__ __launch_bounds__(256)
void k_scores2(const unsigned short* __restrict__ Whb2, const float* __restrict__ a,
               float* __restrict__ sD, float* __restrict__ sS) {
  int wid = (blockIdx.x * blockDim.x + threadIdx.x) >> 6;
  int lane = threadIdx.x & 63;
  if (wid >= N_NODES) return;
  int h = lane >> 4, o = lane & 15;
  float w = __uint_as_float(((unsigned)Whb2[(size_t)wid * D2 + lane]) << 16);
  float pd = w * a[h * 32 + o];
  float ps = w * a[h * 32 + 16 + o];
  #pragma unroll
  for (int s = 8; s; s >>= 1) {
    pd += __shfl_xor(pd, s);
    ps += __shfl_xor(ps, s);
  }
  if (o == 0) {
    sD[wid * 4 + h] = pd;
    sS[wid * 4 + h] = ps;
  }
}

// ============================ layer-1 aggregate ============================
__device__ __forceinline__ float lrelu(float x) { return x > 0.f ? x : 0.2f * x; }
__device__ __forceinline__ float elu(float x)   { return x > 0.f ? x : expm1f(x); }

__global__ __launch_bounds__(256)
void k_agg1(const int* __restrict__ offs, const int* __restrict__ csrsrc,
            const float* __restrict__ sD, const float* __restrict__ sS,
            const float* __restrict__ ab,
            const unsigned short* __restrict__ Whb, float* __restrict__ h1out) {
  int wid = (blockIdx.x * blockDim.x + threadIdx.x) >> 6;
  int lane = threadIdx.x & 63;
  if (wid >= N_NODES) return;
  int h = lane >> 4;
  int beg = offs[wid], end = offs[wid + 1];
  float a0 = 0.f, a1v = 0.f, a2v = 0.f, a3v = 0.f;   // feats 4*lane .. 4*lane+3
  float z = 1.f;
  if (end > beg) {
    float4 dv = ((const float4*)sD)[wid];
    float db0 = dv.x + ab[0], db1 = dv.y + ab[1];
    float db2 = dv.z + ab[2], db3 = dv.w + ab[3];
    // pass 1: per-head max
    float m0 = -1e30f, m1 = -1e30f, m2 = -1e30f, m3 = -1e30f;
    for (int j = beg + lane; j < end; j += 64) {
      int s = csrsrc[j];
      float4 sv = ((const float4*)sS)[s];
      m0 = fmaxf(m0, lrelu(db0 + sv.x));
      m1 = fmaxf(m1, lrelu(db1 + sv.y));
      m2 = fmaxf(m2, lrelu(db2 + sv.z));
      m3 = fmaxf(m3, lrelu(db3 + sv.w));
    }
    #pragma unroll
    for (int o = 32; o; o >>= 1) {
      m0 = fmaxf(m0, __shfl_xor(m0, o));
      m1 = fmaxf(m1, __shfl_xor(m1, o));
      m2 = fmaxf(m2, __shfl_xor(m2, o));
      m3 = fmaxf(m3, __shfl_xor(m3, o));
    }
    // pass 2: exp weights + bf16 gather-aggregate
    float z0 = 0.f, z1 = 0.f, z2 = 0.f, z3 = 0.f;
    for (int cbeg = beg; cbeg < end; cbeg += 64) {
      int j = cbeg + lane;
      int cnt = end - cbeg; if (cnt > 64) cnt = 64;
      float4 ex = make_float4(0.f, 0.f, 0.f, 0.f);
      int sid = 0;
      if (j < end) {
        sid = csrsrc[j];
        float4 sv = ((const float4*)sS)[sid];
        ex.x = expf(lrelu(db0 + sv.x) - m0);
        ex.y = expf(lrelu(db1 + sv.y) - m1);
        ex.z = expf(lrelu(db2 + sv.z) - m2);
        ex.w = expf(lrelu(db3 + sv.w) - m3);
        z0 += ex.x; z1 += ex.y; z2 += ex.z; z3 += ex.w;
      }
      for (int q = 0; q < cnt; ++q) {
        int s = __shfl(sid, q);
        float w0 = __shfl(ex.x, q);
        float w1 = __shfl(ex.y, q);
        float w2 = __shfl(ex.z, q);
        float w3 = __shfl(ex.w, q);
        float w = (h == 0) ? w0 : (h == 1) ? w1 : (h == 2) ? w2 : w3;
        uint2 p = *(const uint2*)(Whb + ((size_t)s << 8) + lane * 4);
        a0  = fmaf(w, bflo(p.x), a0);
        a1v = fmaf(w, bfhi(p.x), a1v);
        a2v = fmaf(w, bflo(p.y), a2v);
        a3v = fmaf(w, bfhi(p.y), a3v);
      }
    }
    #pragma unroll
    for (int o = 32; o; o >>= 1) {
      z0 += __shfl_xor(z0, o);
      z1 += __shfl_xor(z1, o);
      z2 += __shfl_xor(z2, o);
      z3 += __shfl_xor(z3, o);
    }
    z = (h == 0) ? z0 : (h == 1) ? z1 : (h == 2) ? z2 : z3;
  }
  float4 o4 = make_float4(elu(a0 / z), elu(a1v / z), elu(a2v / z), elu(a3v / z));
  ((float4*)(h1out + (size_t)wid * D1))[lane] = o4;
}

// ============================ layer-2 aggregate + softmax + partial mean ====
__global__ __launch_bounds__(256)
void k_agg2(const int* __restrict__ offs, const int* __restrict__ csrsrc,
            const float* __restrict__ sD, const float* __restrict__ sS,
            const float* __restrict__ ab,
            const unsigned short* __restrict__ Whb2, float* __restrict__ partials) {
  __shared__ float red[4][16];
  int widInBlk = threadIdx.x >> 6;
  int wid = blockIdx.x * 4 + widInBlk;
  int lane = threadIdx.x & 63;
  int h = lane >> 4, o = lane & 15;
  float p = 0.f;
  bool active = wid < N_NODES;
  if (active) {
    float val = 0.f;
    int beg = offs[wid], end = offs[wid + 1];
    if (end > beg) {
      float4 dv = ((const float4*)sD)[wid];
      float db0 = dv.x + ab[0], db1 = dv.y + ab[1];
      float db2 = dv.z + ab[2], db3 = dv.w + ab[3];
      float m0 = -1e30f, m1 = -1e30f, m2 = -1e30f, m3 = -1e30f;
      for (int j = beg + lane; j < end; j += 64) {
        int s = csrsrc[j];
        float4 sv = ((const float4*)sS)[s];
        m0 = fmaxf(m0, lrelu(db0 + sv.x));
        m1 = fmaxf(m1, lrelu(db1 + sv.y));
        m2 = fmaxf(m2, lrelu(db2 + sv.z));
        m3 = fmaxf(m3, lrelu(db3 + sv.w));
      }
      #pragma unroll
      for (int s = 32; s; s >>= 1) {
        m0 = fmaxf(m0, __shfl_xor(m0, s));
        m1 = fmaxf(m1, __shfl_xor(m1, s));
        m2 = fmaxf(m2, __shfl_xor(m2, s));
        m3 = fmaxf(m3, __shfl_xor(m3, s));
      }
      float acc = 0.f;
      float z0 = 0.f, z1 = 0.f, z2 = 0.f, z3 = 0.f;
      for (int cbeg = beg; cbeg < end; cbeg += 64) {
        int j = cbeg + lane;
        int cnt = end - cbeg; if (cnt > 64) cnt = 64;
        float4 ex = make_float4(0.f, 0.f, 0.f, 0.f);
        int sid = 0;
        if (j < end) {
          sid = csrsrc[j];
          float4 sv = ((const float4*)sS)[sid];
          ex.x = expf(lrelu(db0 + sv.x) - m0);
          ex.y = expf(lrelu(db1 + sv.y) - m1);
          ex.z = expf(lrelu(db2 + sv.z) - m2);
          ex.w = expf(lrelu(db3 + sv.w) - m3);
          z0 += ex.x; z1 += ex.y; z2 += ex.z; z3 += ex.w;
        }
        for (int q = 0; q < cnt; ++q) {
          int s = __shfl(sid, q);
          float w0 = __shfl(ex.x, q);
          float w1 = __shfl(ex.y, q);
          float w2 = __shfl(ex.z, q);
          float w3 = __shfl(ex.w, q);
          float w = (h == 0) ? w0 : (h == 1) ? w1 : (h == 2) ? w2 : w3;
          float f = __uint_as_float(((unsigned)Whb2[(size_t)s * D2 + lane]) << 16);
          acc = fmaf(w, f, acc);
        }
      }
      #pragma unroll
      for (int s = 32; s; s >>= 1) {
        z0 += __shfl_xor(z0, s);
        z1 += __shfl_xor(z1, s);
        z2 += __shfl_xor(z2, s);
        z3 += __shfl_xor(z3, s);
      }
      float zh = (h == 0) ? z0 : (h == 1) ? z1 : (h == 2) ? z2 : z3;
      val = acc / zh;
    }
    val += __shfl_xor(val, 16);
    val += __shfl_xor(val, 32);
    val *= 0.25f;
    float mx = val;
    #pragma unroll
    for (int s = 8; s; s >>= 1) mx = fmaxf(mx, __shfl_xor(mx, s));
    float ev = expf(val - mx);
    float ssum = ev;
    #pragma unroll
    for (int s = 8; s; s >>= 1) ssum += __shfl_xor(ssum, s);
    p = ev / ssum;
  }
  if (lane < 16) red[widInBlk][lane] = active ? p : 0.f;
  __syncthreads();
  if (threadIdx.x < 16) {
    partials[(size_t)blockIdx.x * 16 + threadIdx.x] =
        red[0][threadIdx.x] + red[1][threadIdx.x] +
        red[2][threadIdx.x] + red[3][threadIdx.x];
  }
}

// ============== hierarchical final reduce: 25000 -> 128 -> fc ==============
__global__ __launch_bounds__(256)
void k_reduce1(const float* __restrict__ partials, int nrows,
               float* __restrict__ out) {
  __shared__ float red[16][17];
  int t = threadIdx.x;
  int c = t & 15, rl = t >> 4;
  int per = (nrows + RB1 - 1) / RB1;
  int rbeg = blockIdx.x * per;
  int rend = rbeg + per; if (rend > nrows) rend = nrows;
  float s = 0.f;
  for (int r = rbeg + rl; r < rend; r += 16) s += partials[(size_t)r * 16 + c];
  red[rl][c] = s;
  __syncthreads();
  for (int st = 8; st; st >>= 1) {
    if (rl < st) red[rl][c] += red[rl + st][c];
    __syncthreads();
  }
  if (t < 16) out[(size_t)blockIdx.x * 16 + t] = red[0][t];
}

__global__ __launch_bounds__(256)
void k_final(const float* __restrict__ partials,
             const float* __restrict__ fcw, const float* __restrict__ fcb,
             float* __restrict__ out) {
  __shared__ float red[16][17];
  __shared__ float hg[16];
  int t = threadIdx.x;
  int c = t & 15, rl = t >> 4;
  float s = 0.f;
  for (int r = rl; r < RB1; r += 16) s += partials[(size_t)r * 16 + c];
  red[rl][c] = s;
  __syncthreads();
  for (int st = 8; st; st >>= 1) {
    if (rl < st) red[rl][c] += red[rl + st][c];
    __syncthreads();
  }
  if (t < 16) hg[t] = red[0][t] * (1.0f / N_NODES);
  __syncthreads();
  if (t < 16) {
    float acc = fcb[t];
    #pragma unroll
    for (int k = 0; k < 16; ++k) acc += hg[k] * fcw[t * 16 + k];
    out[t] = acc;
  }
}

// ============================ launcher ============================
extern "C" void kernel_launch(void* const* d_in, const int* in_sizes, int n_in,
                              void* d_out, int out_size, void* d_ws, size_t ws_size,
                              hipStream_t stream) {
  const float* h   = (const float*)d_in[0];
  const int*   src = (const int*)  d_in[1];
  const int*   dst = (const int*)  d_in[2];
  const float* W1  = (const float*)d_in[3];
  const float* b1  = (const float*)d_in[4];
  const float* a1  = (const float*)d_in[5];
  const float* ab1 = (const float*)d_in[6];
  const float* W2  = (const float*)d_in[7];
  const float* b2  = (const float*)d_in[8];
  const float* a2  = (const float*)d_in[9];
  const float* ab2 = (const float*)d_in[10];
  const float* fcw = (const float*)d_in[11];
  const float* fcb = (const float*)d_in[12];
  float* out = (float*)d_out;

  char* ws = (char*)d_ws;
  size_t off = 0;
  auto alloc = [&](size_t bytes) -> char* {
    char* p = ws + off;
    off += (bytes + 255) & ~(size_t)255;
    return p;
  };
  unsigned short* Whb1 = (unsigned short*)alloc((size_t)N_NODES * D1 * 2); // 51.2 MB
  float* h1            = (float*)alloc((size_t)N_NODES * D1 * 4);          // 102.4 MB
  unsigned short* Whb2 = (unsigned short*)alloc((size_t)N_NODES * D2 * 2); // 12.8 MB
  float* sD1 = (float*)alloc((size_t)N_NODES * 4 * 4);
  float* sS1 = (float*)alloc((size_t)N_NODES * 4 * 4);
  float* sD2 = (float*)alloc((size_t)N_NODES * 4 * 4);
  float* sS2 = (float*)alloc((size_t)N_NODES * 4 * 4);
  int* counts = (int*)alloc((size_t)N_NODES_PAD * 4);
  int* offs   = (int*)alloc((size_t)(N_NODES + 1) * 4);
  int* cursor = (int*)alloc((size_t)N_NODES * 4);
  int* csrsrc = (int*)alloc((size_t)N_EDGES * 4);
  int* btot   = (int*)alloc((size_t)SCAN_NB * 4);
  int* bbase  = (int*)alloc((size_t)SCAN_NB * 4);
  const int nblk_node = (N_NODES + 3) / 4;   // 25000
  float* partials  = (float*)alloc((size_t)nblk_node * 16 * 4);
  float* partials2 = (float*)alloc((size_t)RB1 * 16 * 4);

  // --- CSR build (by dst) ---
  k_zero_i32<<<(N_NODES_PAD + 255) / 256, 256, 0, stream>>>(counts, N_NODES_PAD);
  k_count<<<(N_EDGES + 255) / 256, 256, 0, stream>>>(dst, counts);
  k_scanA<<<SCAN_NB, 256, 0, stream>>>(counts, btot);
  k_scanB<<<1, 128, 0, stream>>>(btot, bbase, offs);
  k_scanC<<<SCAN_NB, 256, 0, stream>>>(counts, bbase, offs, cursor);
  k_scatter<<<(N_EDGES + 255) / 256, 256, 0, stream>>>(src, dst, cursor, csrsrc);

  // --- layer 1 ---
  k_gemm1<<<dim3((N_NODES + 127) / 128, 2), 256, 0, stream>>>(h, W1, b1, Whb1);
  k_scores1<<<nblk_node, 256, 0, stream>>>(Whb1, a1, sD1, sS1);
  k_agg1<<<nblk_node, 256, 0, stream>>>(offs, csrsrc, sD1, sS1, ab1, Whb1, h1);

  // --- layer 2 ---
  k_gemm2<<<dim3((N_NODES + 127) / 128, 1), 256, 0, stream>>>(h1, W2, b2, Whb2);
  k_scores2<<<nblk_node, 256, 0, stream>>>(Whb2, a2, sD2, sS2);
  k_agg2<<<nblk_node, 256, 0, stream>>>(offs, csrsrc, sD2, sS2, ab2, Whb2, partials);

  // --- readout ---
  k_reduce1<<<RB1, 256, 0, stream>>>(partials, nblk_node, partials2);
  k_final<<<1, 256, 0, stream>>>(partials2, fcw, fcb, out);
}

// Round 4
// 700.135 us; speedup vs baseline: 2.1325x; 1.1328x over previous
//
#include <hip/hip_runtime.h>
#include <math.h>

#define N_NODES  100000
#define N_EDGES  1600000
#define IN_F     128
#define HID      64
#define HEADS    4
#define NCLS     16
#define D1       (HEADS*HID)    // 256
#define D2       (HEADS*NCLS)   // 64

#define SCAN_CHUNK 1024
#define SCAN_NB    ((N_NODES + SCAN_CHUNK - 1) / SCAN_CHUNK)   // 98
#define N_NODES_PAD (SCAN_NB * SCAN_CHUNK)                     // 100352
#define RB1 128   // reduce-stage-1 blocks

// bf16 helpers (RNE)
__device__ __forceinline__ unsigned bf16rne(float x) {
  unsigned u = __float_as_uint(x);
  return (u + 0x7fffu + ((u >> 16) & 1u)) >> 16;
}
__device__ __forceinline__ unsigned packbf2(float lo, float hi) {
  return bf16rne(lo) | (bf16rne(hi) << 16);
}
__device__ __forceinline__ float bflo(unsigned p) { return __uint_as_float(p << 16); }
__device__ __forceinline__ float bfhi(unsigned p) { return __uint_as_float(p & 0xffff0000u); }

// ============================ CSR build ============================
__global__ void k_zero_i32(int* __restrict__ p, int n) {
  int i = blockIdx.x * blockDim.x + threadIdx.x;
  if (i < n) p[i] = 0;
}

__global__ void k_count(const int* __restrict__ dst, int* __restrict__ counts) {
  int i = blockIdx.x * blockDim.x + threadIdx.x;
  if (i < N_EDGES) atomicAdd(&counts[dst[i]], 1);
}

__global__ __launch_bounds__(256)
void k_scanA(const int* __restrict__ counts, int* __restrict__ btot) {
  __shared__ int red[256];
  int t = threadIdx.x;
  const int4* cp = (const int4*)(counts + blockIdx.x * SCAN_CHUNK);
  int4 v = cp[t];
  red[t] = v.x + v.y + v.z + v.w;
  __syncthreads();
  for (int s = 128; s; s >>= 1) {
    if (t < s) red[t] += red[t + s];
    __syncthreads();
  }
  if (t == 0) btot[blockIdx.x] = red[0];
}

__global__ __launch_bounds__(128)
void k_scanB(const int* __restrict__ btot, int* __restrict__ bbase,
             int* __restrict__ offs) {
  __shared__ int part[128];
  int t = threadIdx.x;
  part[t] = (t < SCAN_NB) ? btot[t] : 0;
  __syncthreads();
  for (int o = 1; o < 128; o <<= 1) {
    int v = (t >= o) ? part[t - o] : 0;
    __syncthreads();
    part[t] += v;
    __syncthreads();
  }
  if (t < SCAN_NB) bbase[t] = (t == 0) ? 0 : part[t - 1];
  if (t == 0) offs[N_NODES] = N_EDGES;
}

__global__ __launch_bounds__(256)
void k_scanC(const int* __restrict__ counts, const int* __restrict__ bbase,
             int* __restrict__ offs, int* __restrict__ cursor) {
  __shared__ int part[256];
  int t = threadIdx.x;
  int gbase = blockIdx.x * SCAN_CHUNK;
  const int4* cp = (const int4*)(counts + gbase);
  int4 v = cp[t];
  int tot = v.x + v.y + v.z + v.w;
  part[t] = tot;
  __syncthreads();
  for (int o = 1; o < 256; o <<= 1) {
    int q = (t >= o) ? part[t - o] : 0;
    __syncthreads();
    part[t] += q;
    __syncthreads();
  }
  int run = bbase[blockIdx.x] + part[t] - tot;
  int i0 = gbase + t * 4;
  int o0 = run;
  int o1 = o0 + v.x;
  int o2 = o1 + v.y;
  int o3 = o2 + v.z;
  if (i0 + 0 < N_NODES) { offs[i0 + 0] = o0; cursor[i0 + 0] = o0; }
  if (i0 + 1 < N_NODES) { offs[i0 + 1] = o1; cursor[i0 + 1] = o1; }
  if (i0 + 2 < N_NODES) { offs[i0 + 2] = o2; cursor[i0 + 2] = o2; }
  if (i0 + 3 < N_NODES) { offs[i0 + 3] = o3; cursor[i0 + 3] = o3; }
}

__global__ void k_scatter(const int* __restrict__ src, const int* __restrict__ dst,
                          int* __restrict__ cursor, int* __restrict__ csrsrc) {
  int i = blockIdx.x * blockDim.x + threadIdx.x;
  if (i < N_EDGES) {
    int p = atomicAdd(&cursor[dst[i]], 1);
    csrsrc[p] = src[i];
  }
}

// ============================ GEMM 1 ============================
// Whb[N,256] (bf16) = A[N,128] * B (+bias); B[f,c] = W1[(c>>6)*8192 + f*64 + (c&63)]
#define BK 32
__global__ __launch_bounds__(256)
void k_gemm1(const float* __restrict__ A, const float* __restrict__ W,
             const float* __restrict__ bias, unsigned short* __restrict__ Whb) {
  __shared__ float As[BK][128 + 4];
  __shared__ float Bs[BK][128 + 4];
  int t = threadIdx.x;
  int row0 = blockIdx.x * 128;
  int col0 = blockIdx.y * 128;
  int tr = t >> 4, tc = t & 15;
  float acc[8][8] = {};
  int ar = t >> 1;
  int ac = (t & 1) * 16;

  for (int kk = 0; kk < IN_F; kk += BK) {
    __syncthreads();
    {
      int grow = row0 + ar;
      float av[16];
      if (grow < N_NODES) {
        const float4* ap = (const float4*)(A + (size_t)grow * IN_F + kk + ac);
        *(float4*)&av[0]  = ap[0];
        *(float4*)&av[4]  = ap[1];
        *(float4*)&av[8]  = ap[2];
        *(float4*)&av[12] = ap[3];
      } else {
        #pragma unroll
        for (int u = 0; u < 16; ++u) av[u] = 0.f;
      }
      #pragma unroll
      for (int u = 0; u < 16; ++u) As[ac + u][ar] = av[u];
    }
    #pragma unroll
    for (int j = 0; j < 4; ++j) {
      int s = t + j * 256;
      int f = s >> 5;
      int c = (s & 31) * 4;
      int gc = col0 + c;
      const float* wp = W + ((gc >> 6) << 13) + ((size_t)(kk + f) << 6) + (gc & 63);
      *(float4*)&Bs[f][c] = *(const float4*)wp;
    }
    __syncthreads();
    for (int k = 0; k < BK; ++k) {
      float av[8], bv[8];
      *(float4*)&av[0] = *(float4*)&As[k][tr * 8];
      *(float4*)&av[4] = *(float4*)&As[k][tr * 8 + 4];
      *(float4*)&bv[0] = *(float4*)&Bs[k][tc * 8];
      *(float4*)&bv[4] = *(float4*)&Bs[k][tc * 8 + 4];
      #pragma unroll
      for (int i = 0; i < 8; ++i)
        #pragma unroll
        for (int j = 0; j < 8; ++j)
          acc[i][j] = fmaf(av[i], bv[j], acc[i][j]);
    }
  }
  float4 bb0 = *(const float4*)&bias[col0 + tc * 8];
  float4 bb1 = *(const float4*)&bias[col0 + tc * 8 + 4];
  #pragma unroll
  for (int i = 0; i < 8; ++i) {
    int grow = row0 + tr * 8 + i;
    if (grow < N_NODES) {
      uint4 o;
      o.x = packbf2(acc[i][0] + bb0.x, acc[i][1] + bb0.y);
      o.y = packbf2(acc[i][2] + bb0.z, acc[i][3] + bb0.w);
      o.z = packbf2(acc[i][4] + bb1.x, acc[i][5] + bb1.y);
      o.w = packbf2(acc[i][6] + bb1.z, acc[i][7] + bb1.w);
      *(uint4*)(Whb + (size_t)grow * D1 + col0 + tc * 8) = o;
    }
  }
}

// ============================ GEMM 2 ============================
// Whb2[N,64] (bf16) = Ab[N,256](bf16) * B (+bias); B[f,c] = W2[(c>>4)*4096 + f*16 + (c&15)]
__global__ __launch_bounds__(256)
void k_gemm2(const unsigned short* __restrict__ Ab, const float* __restrict__ W,
             const float* __restrict__ bias, unsigned short* __restrict__ Whb2) {
  __shared__ float As[BK][128 + 4];
  __shared__ float Bs[BK][64 + 4];
  int t = threadIdx.x;
  int row0 = blockIdx.x * 128;
  int tr = t >> 4, tc = t & 15;
  float acc[8][4] = {};
  int ar = t >> 1;
  int ac = (t & 1) * 16;

  for (int kk = 0; kk < D1; kk += BK) {
    __syncthreads();
    {
      int grow = row0 + ar;
      float av[16];
      if (grow < N_NODES) {
        const uint4* ap = (const uint4*)(Ab + (size_t)grow * D1 + kk + ac);
        uint4 q0 = ap[0];
        uint4 q1 = ap[1];
        av[0]  = bflo(q0.x); av[1]  = bfhi(q0.x);
        av[2]  = bflo(q0.y); av[3]  = bfhi(q0.y);
        av[4]  = bflo(q0.z); av[5]  = bfhi(q0.z);
        av[6]  = bflo(q0.w); av[7]  = bfhi(q0.w);
        av[8]  = bflo(q1.x); av[9]  = bfhi(q1.x);
        av[10] = bflo(q1.y); av[11] = bfhi(q1.y);
        av[12] = bflo(q1.z); av[13] = bfhi(q1.z);
        av[14] = bflo(q1.w); av[15] = bfhi(q1.w);
      } else {
        #pragma unroll
        for (int u = 0; u < 16; ++u) av[u] = 0.f;
      }
      #pragma unroll
      for (int u = 0; u < 16; ++u) As[ac + u][ar] = av[u];
    }
    #pragma unroll
    for (int j = 0; j < 2; ++j) {
      int s = t + j * 256;
      int f = s >> 4;
      int c = (s & 15) * 4;
      const float* wp = W + ((c >> 4) << 12) + ((size_t)(kk + f) << 4) + (c & 15);
      *(float4*)&Bs[f][c] = *(const float4*)wp;
    }
    __syncthreads();
    for (int k = 0; k < BK; ++k) {
      float av[8], bv[4];
      *(float4*)&av[0] = *(float4*)&As[k][tr * 8];
      *(float4*)&av[4] = *(float4*)&As[k][tr * 8 + 4];
      *(float4*)&bv[0] = *(float4*)&Bs[k][tc * 4];
      #pragma unroll
      for (int i = 0; i < 8; ++i)
        #pragma unroll
        for (int j = 0; j < 4; ++j)
          acc[i][j] = fmaf(av[i], bv[j], acc[i][j]);
    }
  }
  float4 bb = *(const float4*)&bias[tc * 4];
  #pragma unroll
  for (int i = 0; i < 8; ++i) {
    int grow = row0 + tr * 8 + i;
    if (grow < N_NODES) {
      uint2 o;
      o.x = packbf2(acc[i][0] + bb.x, acc[i][1] + bb.y);
      o.y = packbf2(acc[i][2] + bb.z, acc[i][3] + bb.w);
      *(uint2*)(Whb2 + (size_t)grow * D2 + tc * 4) = o;
    }
  }
}

// ============================ per-node scores ============================
__global__ __launch_bounds__(256)
void k_scores1(const unsigned short* __restrict__ Whb, const float* __restrict__ a,
               float* __restrict__ sD, float* __restrict__ sS) {
  int wid = (blockIdx.x * blockDim.x + threadIdx.x) >> 6;
  int lane = threadIdx.x & 63;
  if (wid >= N_NODES) return;
  int h = lane >> 4;
  uint2 p = *(const uint2*)(Whb + (size_t)wid * D1 + lane * 4);
  float f0 = bflo(p.x), f1 = bfhi(p.x), f2 = bflo(p.y), f3 = bfhi(p.y);
  int o0 = (lane & 15) * 4;
  const float* ah = a + h * 128;
  float pd = f0 * ah[o0] + f1 * ah[o0 + 1] + f2 * ah[o0 + 2] + f3 * ah[o0 + 3];
  float ps = f0 * ah[64 + o0] + f1 * ah[64 + o0 + 1] + f2 * ah[64 + o0 + 2] + f3 * ah[64 + o0 + 3];
  #pragma unroll
  for (int s = 8; s; s >>= 1) {
    pd += __shfl_xor(pd, s);
    ps += __shfl_xor(ps, s);
  }
  float4 dv = make_float4(__shfl(pd, 0), __shfl(pd, 16), __shfl(pd, 32), __shfl(pd, 48));
  float4 sv = make_float4(__shfl(ps, 0), __shfl(ps, 16), __shfl(ps, 32), __shfl(ps, 48));
  if (lane == 0) {
    ((float4*)sD)[wid] = dv;
    ((float4*)sS)[wid] = sv;
  }
}

__global__ __launch_bounds__(256)
void k_scores2(const unsigned short* __restrict__ Whb2, const float* __restrict__ a,
               float* __restrict__ sD, float* __restrict__ sS) {
  int wid = (blockIdx.x * blockDim.x + threadIdx.x) >> 6;
  int lane = threadIdx.x & 63;
  if (wid >= N_NODES) return;
  int h = lane >> 4, o = lane & 15;
  float w = __uint_as_float(((unsigned)Whb2[(size_t)wid * D2 + lane]) << 16);
  float pd = w * a[h * 32 + o];
  float ps = w * a[h * 32 + 16 + o];
  #pragma unroll
  for (int s = 8; s; s >>= 1) {
    pd += __shfl_xor(pd, s);
    ps += __shfl_xor(ps, s);
  }
  if (o == 0) {
    sD[wid * 4 + h] = pd;
    sS[wid * 4 + h] = ps;
  }
}

// ============================ layer-1 aggregate ============================
__device__ __forceinline__ float lrelu(float x) { return x > 0.f ? x : 0.2f * x; }
__device__ __forceinline__ float elu(float x)   { return x > 0.f ? x : expm1f(x); }

// one wave per node; single pass (no max subtraction), LDS-staged edge weights
__global__ __launch_bounds__(256)
void k_agg1(const int* __restrict__ offs, const int* __restrict__ csrsrc,
            const float* __restrict__ sD, const float* __restrict__ sS,
            const float* __restrict__ ab,
            const unsigned short* __restrict__ Whb, unsigned short* __restrict__ h1out) {
  __shared__ float exbuf[4][64 * 4];
  __shared__ int   sidbuf[4][64];
  int wv = threadIdx.x >> 6;
  int wid = blockIdx.x * 4 + wv;
  int lane = threadIdx.x & 63;
  if (wid >= N_NODES) return;
  int h = lane >> 4;
  int beg = offs[wid], end = offs[wid + 1];
  float a0 = 0.f, a1v = 0.f, a2v = 0.f, a3v = 0.f;   // feats 4*lane..4*lane+3
  float z = 1.f;
  if (end > beg) {
    float4 dv = ((const float4*)sD)[wid];
    float db0 = dv.x + ab[0], db1 = dv.y + ab[1];
    float db2 = dv.z + ab[2], db3 = dv.w + ab[3];
    float z0 = 0.f, z1 = 0.f, z2 = 0.f, z3 = 0.f;
    const int* sb = sidbuf[wv];
    const float* eb = &exbuf[wv][h];
    for (int cbeg = beg; cbeg < end; cbeg += 64) {
      int j = cbeg + lane;
      int cnt = end - cbeg; if (cnt > 64) cnt = 64;
      if (j < end) {
        int sid = csrsrc[j];
        float4 sv = ((const float4*)sS)[sid];
        float e0 = __expf(lrelu(db0 + sv.x));
        float e1 = __expf(lrelu(db1 + sv.y));
        float e2 = __expf(lrelu(db2 + sv.z));
        float e3 = __expf(lrelu(db3 + sv.w));
        z0 += e0; z1 += e1; z2 += e2; z3 += e3;
        sidbuf[wv][lane] = sid;
        *(float4*)&exbuf[wv][lane * 4] = make_float4(e0, e1, e2, e3);
      }
      int q = 0;
      for (; q + 2 <= cnt; q += 2) {
        int s0 = sb[q], s1 = sb[q + 1];
        float w0 = eb[q * 4], w1 = eb[q * 4 + 4];
        uint2 p0 = *(const uint2*)(Whb + (((size_t)s0) << 8) + (lane << 2));
        uint2 p1 = *(const uint2*)(Whb + (((size_t)s1) << 8) + (lane << 2));
        // lo: exact; hi: raw dword (bf16 + mantissa-extension noise < 2^-7 rel)
        a0  = fmaf(w0, __uint_as_float(p0.x << 16), a0);
        a1v = fmaf(w0, __uint_as_float(p0.x), a1v);
        a2v = fmaf(w0, __uint_as_float(p0.y << 16), a2v);
        a3v = fmaf(w0, __uint_as_float(p0.y), a3v);
        a0  = fmaf(w1, __uint_as_float(p1.x << 16), a0);
        a1v = fmaf(w1, __uint_as_float(p1.x), a1v);
        a2v = fmaf(w1, __uint_as_float(p1.y << 16), a2v);
        a3v = fmaf(w1, __uint_as_float(p1.y), a3v);
      }
      if (q < cnt) {
        int s0 = sb[q];
        float w0 = eb[q * 4];
        uint2 p0 = *(const uint2*)(Whb + (((size_t)s0) << 8) + (lane << 2));
        a0  = fmaf(w0, __uint_as_float(p0.x << 16), a0);
        a1v = fmaf(w0, __uint_as_float(p0.x), a1v);
        a2v = fmaf(w0, __uint_as_float(p0.y << 16), a2v);
        a3v = fmaf(w0, __uint_as_float(p0.y), a3v);
      }
    }
    #pragma unroll
    for (int o = 32; o; o >>= 1) {
      z0 += __shfl_xor(z0, o);
      z1 += __shfl_xor(z1, o);
      z2 += __shfl_xor(z2, o);
      z3 += __shfl_xor(z3, o);
    }
    z = (h == 0) ? z0 : (h == 1) ? z1 : (h == 2) ? z2 : z3;
  }
  float o0 = elu(a0 / z), o1 = elu(a1v / z), o2 = elu(a2v / z), o3 = elu(a3v / z);
  uint2 o;
  o.x = packbf2(o0, o1);
  o.y = packbf2(o2, o3);
  *(uint2*)(h1out + (size_t)wid * D1 + lane * 4) = o;
}

// ============================ layer-2 aggregate + softmax + partial mean ====
__global__ __launch_bounds__(256)
void k_agg2(const int* __restrict__ offs, const int* __restrict__ csrsrc,
            const float* __restrict__ sD, const float* __restrict__ sS,
            const float* __restrict__ ab,
            const unsigned short* __restrict__ Whb2, float* __restrict__ partials) {
  __shared__ float exbuf[4][64 * 4];
  __shared__ int   sidbuf[4][64];
  __shared__ float red[4][16];
  int wv = threadIdx.x >> 6;
  int wid = blockIdx.x * 4 + wv;
  int lane = threadIdx.x & 63;
  int h = lane >> 4, o = lane & 15;
  float p = 0.f;
  bool active = wid < N_NODES;
  if (active) {
    float val = 0.f;
    int beg = offs[wid], end = offs[wid + 1];
    if (end > beg) {
      float4 dv = ((const float4*)sD)[wid];
      float db0 = dv.x + ab[0], db1 = dv.y + ab[1];
      float db2 = dv.z + ab[2], db3 = dv.w + ab[3];
      float acc = 0.f;
      float z0 = 0.f, z1 = 0.f, z2 = 0.f, z3 = 0.f;
      const int* sb = sidbuf[wv];
      const float* eb = &exbuf[wv][h];
      for (int cbeg = beg; cbeg < end; cbeg += 64) {
        int j = cbeg + lane;
        int cnt = end - cbeg; if (cnt > 64) cnt = 64;
        if (j < end) {
          int sid = csrsrc[j];
          float4 sv = ((const float4*)sS)[sid];
          float e0 = __expf(lrelu(db0 + sv.x));
          float e1 = __expf(lrelu(db1 + sv.y));
          float e2 = __expf(lrelu(db2 + sv.z));
          float e3 = __expf(lrelu(db3 + sv.w));
          z0 += e0; z1 += e1; z2 += e2; z3 += e3;
          sidbuf[wv][lane] = sid;
          *(float4*)&exbuf[wv][lane * 4] = make_float4(e0, e1, e2, e3);
        }
        int q = 0;
        for (; q + 2 <= cnt; q += 2) {
          int s0 = sb[q], s1 = sb[q + 1];
          float w0 = eb[q * 4], w1 = eb[q * 4 + 4];
          float f0 = __uint_as_float(((unsigned)Whb2[(((size_t)s0) << 6) + lane]) << 16);
          float f1 = __uint_as_float(((unsigned)Whb2[(((size_t)s1) << 6) + lane]) << 16);
          acc = fmaf(w0, f0, acc);
          acc = fmaf(w1, f1, acc);
        }
        if (q < cnt) {
          int s0 = sb[q];
          float w0 = eb[q * 4];
          float f0 = __uint_as_float(((unsigned)Whb2[(((size_t)s0) << 6) + lane]) << 16);
          acc = fmaf(w0, f0, acc);
        }
      }
      #pragma unroll
      for (int s = 32; s; s >>= 1) {
        z0 += __shfl_xor(z0, s);
        z1 += __shfl_xor(z1, s);
        z2 += __shfl_xor(z2, s);
        z3 += __shfl_xor(z3, s);
      }
      float zh = (h == 0) ? z0 : (h == 1) ? z1 : (h == 2) ? z2 : z3;
      val = acc / zh;
    }
    val += __shfl_xor(val, 16);
    val += __shfl_xor(val, 32);
    val *= 0.25f;
    float mx = val;
    #pragma unroll
    for (int s = 8; s; s >>= 1) mx = fmaxf(mx, __shfl_xor(mx, s));
    float ev = __expf(val - mx);
    float ssum = ev;
    #pragma unroll
    for (int s = 8; s; s >>= 1) ssum += __shfl_xor(ssum, s);
    p = ev / ssum;
  }
  if (lane < 16) red[wv][lane] = active ? p : 0.f;
  __syncthreads();
  if (threadIdx.x < 16) {
    partials[(size_t)blockIdx.x * 16 + threadIdx.x] =
        red[0][threadIdx.x] + red[1][threadIdx.x] +
        red[2][threadIdx.x] + red[3][threadIdx.x];
  }
}

// ============== hierarchical final reduce: 25000 -> 128 -> fc ==============
__global__ __launch_bounds__(256)
void k_reduce1(const float* __restrict__ partials, int nrows,
               float* __restrict__ out) {
  __shared__ float red[16][17];
  int t = threadIdx.x;
  int c = t & 15, rl = t >> 4;
  int per = (nrows + RB1 - 1) / RB1;
  int rbeg = blockIdx.x * per;
  int rend = rbeg + per; if (rend > nrows) rend = nrows;
  float s = 0.f;
  for (int r = rbeg + rl; r < rend; r += 16) s += partials[(size_t)r * 16 + c];
  red[rl][c] = s;
  __syncthreads();
  for (int st = 8; st; st >>= 1) {
    if (rl < st) red[rl][c] += red[rl + st][c];
    __syncthreads();
  }
  if (t < 16) out[(size_t)blockIdx.x * 16 + t] = red[0][t];
}

__global__ __launch_bounds__(256)
void k_final(const float* __restrict__ partials,
             const float* __restrict__ fcw, const float* __restrict__ fcb,
             float* __restrict__ out) {
  __shared__ float red[16][17];
  __shared__ float hg[16];
  int t = threadIdx.x;
  int c = t & 15, rl = t >> 4;
  float s = 0.f;
  for (int r = rl; r < RB1; r += 16) s += partials[(size_t)r * 16 + c];
  red[rl][c] = s;
  __syncthreads();
  for (int st = 8; st; st >>= 1) {
    if (rl < st) red[rl][c] += red[rl + st][c];
    __syncthreads();
  }
  if (t < 16) hg[t] = red[0][t] * (1.0f / N_NODES);
  __syncthreads();
  if (t < 16) {
    float acc = fcb[t];
    #pragma unroll
    for (int k = 0; k < 16; ++k) acc += hg[k] * fcw[t * 16 + k];
    out[t] = acc;
  }
}

// ============================ launcher ============================
extern "C" void kernel_launch(void* const* d_in, const int* in_sizes, int n_in,
                              void* d_out, int out_size, void* d_ws, size_t ws_size,
                              hipStream_t stream) {
  const float* h   = (const float*)d_in[0];
  const int*   src = (const int*)  d_in[1];
  const int*   dst = (const int*)  d_in[2];
  const float* W1  = (const float*)d_in[3];
  const float* b1  = (const float*)d_in[4];
  const float* a1  = (const float*)d_in[5];
  const float* ab1 = (const float*)d_in[6];
  const float* W2  = (const float*)d_in[7];
  const float* b2  = (const float*)d_in[8];
  const float* a2  = (const float*)d_in[9];
  const float* ab2 = (const float*)d_in[10];
  const float* fcw = (const float*)d_in[11];
  const float* fcb = (const float*)d_in[12];
  float* out = (float*)d_out;

  char* ws = (char*)d_ws;
  size_t off = 0;
  auto alloc = [&](size_t bytes) -> char* {
    char* p = ws + off;
    off += (bytes + 255) & ~(size_t)255;
    return p;
  };
  unsigned short* Whb1 = (unsigned short*)alloc((size_t)N_NODES * D1 * 2); // 51.2 MB
  unsigned short* h1b  = (unsigned short*)alloc((size_t)N_NODES * D1 * 2); // 51.2 MB
  unsigned short* Whb2 = (unsigned short*)alloc((size_t)N_NODES * D2 * 2); // 12.8 MB
  float* sD1 = (float*)alloc((size_t)N_NODES * 4 * 4);
  float* sS1 = (float*)alloc((size_t)N_NODES * 4 * 4);
  float* sD2 = (float*)alloc((size_t)N_NODES * 4 * 4);
  float* sS2 = (float*)alloc((size_t)N_NODES * 4 * 4);
  int* counts = (int*)alloc((size_t)N_NODES_PAD * 4);
  int* offs   = (int*)alloc((size_t)(N_NODES + 1) * 4);
  int* cursor = (int*)alloc((size_t)N_NODES * 4);
  int* csrsrc = (int*)alloc((size_t)N_EDGES * 4);
  int* btot   = (int*)alloc((size_t)SCAN_NB * 4);
  int* bbase  = (int*)alloc((size_t)SCAN_NB * 4);
  const int nblk_node = (N_NODES + 3) / 4;   // 25000
  float* partials  = (float*)alloc((size_t)nblk_node * 16 * 4);
  float* partials2 = (float*)alloc((size_t)RB1 * 16 * 4);

  // --- CSR build (by dst) ---
  k_zero_i32<<<(N_NODES_PAD + 255) / 256, 256, 0, stream>>>(counts, N_NODES_PAD);
  k_count<<<(N_EDGES + 255) / 256, 256, 0, stream>>>(dst, counts);
  k_scanA<<<SCAN_NB, 256, 0, stream>>>(counts, btot);
  k_scanB<<<1, 128, 0, stream>>>(btot, bbase, offs);
  k_scanC<<<SCAN_NB, 256, 0, stream>>>(counts, bbase, offs, cursor);
  k_scatter<<<(N_EDGES + 255) / 256, 256, 0, stream>>>(src, dst, cursor, csrsrc);

  // --- layer 1 ---
  k_gemm1<<<dim3((N_NODES + 127) / 128, 2), 256, 0, stream>>>(h, W1, b1, Whb1);
  k_scores1<<<nblk_node, 256, 0, stream>>>(Whb1, a1, sD1, sS1);
  k_agg1<<<nblk_node, 256, 0, stream>>>(offs, csrsrc, sD1, sS1, ab1, Whb1, h1b);

  // --- layer 2 ---
  k_gemm2<<<dim3((N_NODES + 127) / 128, 1), 256, 0, stream>>>(h1b, W2, b2, Whb2);
  k_scores2<<<nblk_node, 256, 0, stream>>>(Whb2, a2, sD2, sS2);
  k_agg2<<<nblk_node, 256, 0, stream>>>(offs, csrsrc, sD2, sS2, ab2, Whb2, partials);

  // --- readout ---
  k_reduce1<<<RB1, 256, 0, stream>>>(partials, nblk_node, partials2);
  k_final<<<1, 256, 0, stream>>>(partials2, fcw, fcb, out);
}

// Round 5
// 631.073 us; speedup vs baseline: 2.3658x; 1.1094x over previous
//
#include <hip/hip_runtime.h>
#include <math.h>

#define N_NODES  100000
#define N_EDGES  1600000
#define IN_F     128
#define HID      64
#define HEADS    4
#define NCLS     16
#define D1       (HEADS*HID)    // 256
#define D2       (HEADS*NCLS)   // 64

#define SCAN_CHUNK 1024
#define SCAN_NB    ((N_NODES + SCAN_CHUNK - 1) / SCAN_CHUNK)   // 98
#define N_NODES_PAD (SCAN_NB * SCAN_CHUNK)                     // 100352
#define RB1 128   // reduce-stage-1 blocks

// bf16 helpers (RNE)
__device__ __forceinline__ unsigned bf16rne(float x) {
  unsigned u = __float_as_uint(x);
  return (u + 0x7fffu + ((u >> 16) & 1u)) >> 16;
}
__device__ __forceinline__ unsigned packbf2(float lo, float hi) {
  return bf16rne(lo) | (bf16rne(hi) << 16);
}
__device__ __forceinline__ float bflo(unsigned p) { return __uint_as_float(p << 16); }
__device__ __forceinline__ float bfhi(unsigned p) { return __uint_as_float(p & 0xffff0000u); }

// ============================ CSR build ============================
// cursorPad: one counter per 64B cacheline (stride 16 ints) to kill false sharing
__global__ __launch_bounds__(256)
void k_zero4(int4* __restrict__ p, int n4) {
  int i = blockIdx.x * blockDim.x + threadIdx.x;
  if (i < n4) p[i] = make_int4(0, 0, 0, 0);
}

// count + per-edge rank (atomic return), rank stored coalesced
__global__ __launch_bounds__(256)
void k_count(const int* __restrict__ dst, int* __restrict__ cursorPad,
             int* __restrict__ rank) {
  int i = blockIdx.x * blockDim.x + threadIdx.x;
  if (i < N_EDGES) {
    int d = dst[i];
    rank[i] = atomicAdd(&cursorPad[d << 4], 1);
  }
}

// compact padded counters -> dense counts (zero-padded to N_NODES_PAD)
__global__ __launch_bounds__(256)
void k_compact(const int* __restrict__ cursorPad, int* __restrict__ counts) {
  int i = blockIdx.x * blockDim.x + threadIdx.x;
  if (i < N_NODES_PAD) counts[i] = (i < N_NODES) ? cursorPad[i << 4] : 0;
}

__global__ __launch_bounds__(256)
void k_scanA(const int* __restrict__ counts, int* __restrict__ btot) {
  __shared__ int red[256];
  int t = threadIdx.x;
  const int4* cp = (const int4*)(counts + blockIdx.x * SCAN_CHUNK);
  int4 v = cp[t];
  red[t] = v.x + v.y + v.z + v.w;
  __syncthreads();
  for (int s = 128; s; s >>= 1) {
    if (t < s) red[t] += red[t + s];
    __syncthreads();
  }
  if (t == 0) btot[blockIdx.x] = red[0];
}

__global__ __launch_bounds__(128)
void k_scanB(const int* __restrict__ btot, int* __restrict__ bbase,
             int* __restrict__ offs) {
  __shared__ int part[128];
  int t = threadIdx.x;
  part[t] = (t < SCAN_NB) ? btot[t] : 0;
  __syncthreads();
  for (int o = 1; o < 128; o <<= 1) {
    int v = (t >= o) ? part[t - o] : 0;
    __syncthreads();
    part[t] += v;
    __syncthreads();
  }
  if (t < SCAN_NB) bbase[t] = (t == 0) ? 0 : part[t - 1];
  if (t == 0) offs[N_NODES] = N_EDGES;
}

__global__ __launch_bounds__(256)
void k_scanC(const int* __restrict__ counts, const int* __restrict__ bbase,
             int* __restrict__ offs) {
  __shared__ int part[256];
  int t = threadIdx.x;
  int gbase = blockIdx.x * SCAN_CHUNK;
  const int4* cp = (const int4*)(counts + gbase);
  int4 v = cp[t];
  int tot = v.x + v.y + v.z + v.w;
  part[t] = tot;
  __syncthreads();
  for (int o = 1; o < 256; o <<= 1) {
    int q = (t >= o) ? part[t - o] : 0;
    __syncthreads();
    part[t] += q;
    __syncthreads();
  }
  int run = bbase[blockIdx.x] + part[t] - tot;
  int i0 = gbase + t * 4;
  int o0 = run;
  int o1 = o0 + v.x;
  int o2 = o1 + v.y;
  int o3 = o2 + v.z;
  if (i0 + 0 < N_NODES) offs[i0 + 0] = o0;
  if (i0 + 1 < N_NODES) offs[i0 + 1] = o1;
  if (i0 + 2 < N_NODES) offs[i0 + 2] = o2;
  if (i0 + 3 < N_NODES) offs[i0 + 3] = o3;
}

// atomic-free scatter: pos = offs[dst] + rank; fire-and-forget store
__global__ __launch_bounds__(256)
void k_scatter(const int* __restrict__ src, const int* __restrict__ dst,
               const int* __restrict__ rank, const int* __restrict__ offs,
               int* __restrict__ csrsrc) {
  int i = blockIdx.x * blockDim.x + threadIdx.x;
  if (i < N_EDGES) {
    csrsrc[offs[dst[i]] + rank[i]] = src[i];
  }
}

// ============================ GEMM 1 ============================
// Whb[N,256] (bf16) = A[N,128] * B (+bias); B[f,c] = W1[(c>>6)*8192 + f*64 + (c&63)]
#define BK 32
__global__ __launch_bounds__(256)
void k_gemm1(const float* __restrict__ A, const float* __restrict__ W,
             const float* __restrict__ bias, unsigned short* __restrict__ Whb) {
  __shared__ float As[BK][128 + 4];
  __shared__ float Bs[BK][128 + 4];
  int t = threadIdx.x;
  int row0 = blockIdx.x * 128;
  int col0 = blockIdx.y * 128;
  int tr = t >> 4, tc = t & 15;
  float acc[8][8] = {};
  int ar = t >> 1;
  int ac = (t & 1) * 16;

  for (int kk = 0; kk < IN_F; kk += BK) {
    __syncthreads();
    {
      int grow = row0 + ar;
      float av[16];
      if (grow < N_NODES) {
        const float4* ap = (const float4*)(A + (size_t)grow * IN_F + kk + ac);
        *(float4*)&av[0]  = ap[0];
        *(float4*)&av[4]  = ap[1];
        *(float4*)&av[8]  = ap[2];
        *(float4*)&av[12] = ap[3];
      } else {
        #pragma unroll
        for (int u = 0; u < 16; ++u) av[u] = 0.f;
      }
      #pragma unroll
      for (int u = 0; u < 16; ++u) As[ac + u][ar] = av[u];
    }
    #pragma unroll
    for (int j = 0; j < 4; ++j) {
      int s = t + j * 256;
      int f = s >> 5;
      int c = (s & 31) * 4;
      int gc = col0 + c;
      const float* wp = W + ((gc >> 6) << 13) + ((size_t)(kk + f) << 6) + (gc & 63);
      *(float4*)&Bs[f][c] = *(const float4*)wp;
    }
    __syncthreads();
    for (int k = 0; k < BK; ++k) {
      float av[8], bv[8];
      *(float4*)&av[0] = *(float4*)&As[k][tr * 8];
      *(float4*)&av[4] = *(float4*)&As[k][tr * 8 + 4];
      *(float4*)&bv[0] = *(float4*)&Bs[k][tc * 8];
      *(float4*)&bv[4] = *(float4*)&Bs[k][tc * 8 + 4];
      #pragma unroll
      for (int i = 0; i < 8; ++i)
        #pragma unroll
        for (int j = 0; j < 8; ++j)
          acc[i][j] = fmaf(av[i], bv[j], acc[i][j]);
    }
  }
  float4 bb0 = *(const float4*)&bias[col0 + tc * 8];
  float4 bb1 = *(const float4*)&bias[col0 + tc * 8 + 4];
  #pragma unroll
  for (int i = 0; i < 8; ++i) {
    int grow = row0 + tr * 8 + i;
    if (grow < N_NODES) {
      uint4 o;
      o.x = packbf2(acc[i][0] + bb0.x, acc[i][1] + bb0.y);
      o.y = packbf2(acc[i][2] + bb0.z, acc[i][3] + bb0.w);
      o.z = packbf2(acc[i][4] + bb1.x, acc[i][5] + bb1.y);
      o.w = packbf2(acc[i][6] + bb1.z, acc[i][7] + bb1.w);
      *(uint4*)(Whb + (size_t)grow * D1 + col0 + tc * 8) = o;
    }
  }
}

// ============================ GEMM 2 ============================
__global__ __launch_bounds__(256)
void k_gemm2(const unsigned short* __restrict__ Ab, const float* __restrict__ W,
             const float* __restrict__ bias, unsigned short* __restrict__ Whb2) {
  __shared__ float As[BK][128 + 4];
  __shared__ float Bs[BK][64 + 4];
  int t = threadIdx.x;
  int row0 = blockIdx.x * 128;
  int tr = t >> 4, tc = t & 15;
  float acc[8][4] = {};
  int ar = t >> 1;
  int ac = (t & 1) * 16;

  for (int kk = 0; kk < D1; kk += BK) {
    __syncthreads();
    {
      int grow = row0 + ar;
      float av[16];
      if (grow < N_NODES) {
        const uint4* ap = (const uint4*)(Ab + (size_t)grow * D1 + kk + ac);
        uint4 q0 = ap[0];
        uint4 q1 = ap[1];
        av[0]  = bflo(q0.x); av[1]  = bfhi(q0.x);
        av[2]  = bflo(q0.y); av[3]  = bfhi(q0.y);
        av[4]  = bflo(q0.z); av[5]  = bfhi(q0.z);
        av[6]  = bflo(q0.w); av[7]  = bfhi(q0.w);
        av[8]  = bflo(q1.x); av[9]  = bfhi(q1.x);
        av[10] = bflo(q1.y); av[11] = bfhi(q1.y);
        av[12] = bflo(q1.z); av[13] = bfhi(q1.z);
        av[14] = bflo(q1.w); av[15] = bfhi(q1.w);
      } else {
        #pragma unroll
        for (int u = 0; u < 16; ++u) av[u] = 0.f;
      }
      #pragma unroll
      for (int u = 0; u < 16; ++u) As[ac + u][ar] = av[u];
    }
    #pragma unroll
    for (int j = 0; j < 2; ++j) {
      int s = t + j * 256;
      int f = s >> 4;
      int c = (s & 15) * 4;
      const float* wp = W + ((c >> 4) << 12) + ((size_t)(kk + f) << 4) + (c & 15);
      *(float4*)&Bs[f][c] = *(const float4*)wp;
    }
    __syncthreads();
    for (int k = 0; k < BK; ++k) {
      float av[8], bv[4];
      *(float4*)&av[0] = *(float4*)&As[k][tr * 8];
      *(float4*)&av[4] = *(float4*)&As[k][tr * 8 + 4];
      *(float4*)&bv[0] = *(float4*)&Bs[k][tc * 4];
      #pragma unroll
      for (int i = 0; i < 8; ++i)
        #pragma unroll
        for (int j = 0; j < 4; ++j)
          acc[i][j] = fmaf(av[i], bv[j], acc[i][j]);
    }
  }
  float4 bb = *(const float4*)&bias[tc * 4];
  #pragma unroll
  for (int i = 0; i < 8; ++i) {
    int grow = row0 + tr * 8 + i;
    if (grow < N_NODES) {
      uint2 o;
      o.x = packbf2(acc[i][0] + bb.x, acc[i][1] + bb.y);
      o.y = packbf2(acc[i][2] + bb.z, acc[i][3] + bb.w);
      *(uint2*)(Whb2 + (size_t)grow * D2 + tc * 4) = o;
    }
  }
}

// ============================ per-node scores ============================
__global__ __launch_bounds__(256)
void k_scores1(const unsigned short* __restrict__ Whb, const float* __restrict__ a,
               float* __restrict__ sD, float* __restrict__ sS) {
  int wid = (blockIdx.x * blockDim.x + threadIdx.x) >> 6;
  int lane = threadIdx.x & 63;
  if (wid >= N_NODES) return;
  int h = lane >> 4;
  uint2 p = *(const uint2*)(Whb + (size_t)wid * D1 + lane * 4);
  float f0 = bflo(p.x), f1 = bfhi(p.x), f2 = bflo(p.y), f3 = bfhi(p.y);
  int o0 = (lane & 15) * 4;
  const float* ah = a + h * 128;
  float pd = f0 * ah[o0] + f1 * ah[o0 + 1] + f2 * ah[o0 + 2] + f3 * ah[o0 + 3];
  float ps = f0 * ah[64 + o0] + f1 * ah[64 + o0 + 1] + f2 * ah[64 + o0 + 2] + f3 * ah[64 + o0 + 3];
  #pragma unroll
  for (int s = 8; s; s >>= 1) {
    pd += __shfl_xor(pd, s);
    ps += __shfl_xor(ps, s);
  }
  float4 dv = make_float4(__shfl(pd, 0), __shfl(pd, 16), __shfl(pd, 32), __shfl(pd, 48));
  float4 sv = make_float4(__shfl(ps, 0), __shfl(ps, 16), __shfl(ps, 32), __shfl(ps, 48));
  if (lane == 0) {
    ((float4*)sD)[wid] = dv;
    ((float4*)sS)[wid] = sv;
  }
}

__global__ __launch_bounds__(256)
void k_scores2(const unsigned short* __restrict__ Whb2, const float* __restrict__ a,
               float* __restrict__ sD, float* __restrict__ sS) {
  int wid = (blockIdx.x * blockDim.x + threadIdx.x) >> 6;
  int lane = threadIdx.x & 63;
  if (wid >= N_NODES) return;
  int h = lane >> 4, o = lane & 15;
  float w = __uint_as_float(((unsigned)Whb2[(size_t)wid * D2 + lane]) << 16);
  float pd = w * a[h * 32 + o];
  float ps = w * a[h * 32 + 16 + o];
  #pragma unroll
  for (int s = 8; s; s >>= 1) {
    pd += __shfl_xor(pd, s);
    ps += __shfl_xor(ps, s);
  }
  if (o == 0) {
    sD[wid * 4 + h] = pd;
    sS[wid * 4 + h] = ps;
  }
}

// ============================ layer-1 aggregate ============================
__device__ __forceinline__ float lrelu(float x) { return x > 0.f ? x : 0.2f * x; }
__device__ __forceinline__ float elu(float x)   { return x > 0.f ? x : expm1f(x); }

// one wave per node; single pass (no max subtraction), LDS-staged edge weights
__global__ __launch_bounds__(256)
void k_agg1(const int* __restrict__ offs, const int* __restrict__ csrsrc,
            const float* __restrict__ sD, const float* __restrict__ sS,
            const float* __restrict__ ab,
            const unsigned short* __restrict__ Whb, unsigned short* __restrict__ h1out) {
  __shared__ float exbuf[4][64 * 4];
  __shared__ int   sidbuf[4][64];
  int wv = threadIdx.x >> 6;
  int wid = blockIdx.x * 4 + wv;
  int lane = threadIdx.x & 63;
  if (wid >= N_NODES) return;
  int h = lane >> 4;
  int beg = offs[wid], end = offs[wid + 1];
  float a0 = 0.f, a1v = 0.f, a2v = 0.f, a3v = 0.f;   // feats 4*lane..4*lane+3
  float z = 1.f;
  if (end > beg) {
    float4 dv = ((const float4*)sD)[wid];
    float db0 = dv.x + ab[0], db1 = dv.y + ab[1];
    float db2 = dv.z + ab[2], db3 = dv.w + ab[3];
    float z0 = 0.f, z1 = 0.f, z2 = 0.f, z3 = 0.f;
    const int* sb = sidbuf[wv];
    const float* eb = &exbuf[wv][h];
    for (int cbeg = beg; cbeg < end; cbeg += 64) {
      int j = cbeg + lane;
      int cnt = end - cbeg; if (cnt > 64) cnt = 64;
      if (j < end) {
        int sid = csrsrc[j];
        float4 sv = ((const float4*)sS)[sid];
        float e0 = __expf(lrelu(db0 + sv.x));
        float e1 = __expf(lrelu(db1 + sv.y));
        float e2 = __expf(lrelu(db2 + sv.z));
        float e3 = __expf(lrelu(db3 + sv.w));
        z0 += e0; z1 += e1; z2 += e2; z3 += e3;
        sidbuf[wv][lane] = sid;
        *(float4*)&exbuf[wv][lane * 4] = make_float4(e0, e1, e2, e3);
      }
      int q = 0;
      for (; q + 2 <= cnt; q += 2) {
        int s0 = sb[q], s1 = sb[q + 1];
        float w0 = eb[q * 4], w1 = eb[q * 4 + 4];
        uint2 p0 = *(const uint2*)(Whb + (((size_t)s0) << 8) + (lane << 2));
        uint2 p1 = *(const uint2*)(Whb + (((size_t)s1) << 8) + (lane << 2));
        a0  = fmaf(w0, __uint_as_float(p0.x << 16), a0);
        a1v = fmaf(w0, __uint_as_float(p0.x), a1v);
        a2v = fmaf(w0, __uint_as_float(p0.y << 16), a2v);
        a3v = fmaf(w0, __uint_as_float(p0.y), a3v);
        a0  = fmaf(w1, __uint_as_float(p1.x << 16), a0);
        a1v = fmaf(w1, __uint_as_float(p1.x), a1v);
        a2v = fmaf(w1, __uint_as_float(p1.y << 16), a2v);
        a3v = fmaf(w1, __uint_as_float(p1.y), a3v);
      }
      if (q < cnt) {
        int s0 = sb[q];
        float w0 = eb[q * 4];
        uint2 p0 = *(const uint2*)(Whb + (((size_t)s0) << 8) + (lane << 2));
        a0  = fmaf(w0, __uint_as_float(p0.x << 16), a0);
        a1v = fmaf(w0, __uint_as_float(p0.x), a1v);
        a2v = fmaf(w0, __uint_as_float(p0.y << 16), a2v);
        a3v = fmaf(w0, __uint_as_float(p0.y), a3v);
      }
    }
    #pragma unroll
    for (int o = 32; o; o >>= 1) {
      z0 += __shfl_xor(z0, o);
      z1 += __shfl_xor(z1, o);
      z2 += __shfl_xor(z2, o);
      z3 += __shfl_xor(z3, o);
    }
    z = (h == 0) ? z0 : (h == 1) ? z1 : (h == 2) ? z2 : z3;
  }
  float o0 = elu(a0 / z), o1 = elu(a1v / z), o2 = elu(a2v / z), o3 = elu(a3v / z);
  uint2 o;
  o.x = packbf2(o0, o1);
  o.y = packbf2(o2, o3);
  *(uint2*)(h1out + (size_t)wid * D1 + lane * 4) = o;
}

// ============================ layer-2 aggregate + softmax + partial mean ====
__global__ __launch_bounds__(256)
void k_agg2(const int* __restrict__ offs, const int* __restrict__ csrsrc,
            const float* __restrict__ sD, const float* __restrict__ sS,
            const float* __restrict__ ab,
            const unsigned short* __restrict__ Whb2, float* __restrict__ partials) {
  __shared__ float exbuf[4][64 * 4];
  __shared__ int   sidbuf[4][64];
  __shared__ float red[4][16];
  int wv = threadIdx.x >> 6;
  int wid = blockIdx.x * 4 + wv;
  int lane = threadIdx.x & 63;
  int h = lane >> 4, o = lane & 15;
  float p = 0.f;
  bool active = wid < N_NODES;
  if (active) {
    float val = 0.f;
    int beg = offs[wid], end = offs[wid + 1];
    if (end > beg) {
      float4 dv = ((const float4*)sD)[wid];
      float db0 = dv.x + ab[0], db1 = dv.y + ab[1];
      float db2 = dv.z + ab[2], db3 = dv.w + ab[3];
      float acc = 0.f;
      float z0 = 0.f, z1 = 0.f, z2 = 0.f, z3 = 0.f;
      const int* sb = sidbuf[wv];
      const float* eb = &exbuf[wv][h];
      for (int cbeg = beg; cbeg < end; cbeg += 64) {
        int j = cbeg + lane;
        int cnt = end - cbeg; if (cnt > 64) cnt = 64;
        if (j < end) {
          int sid = csrsrc[j];
          float4 sv = ((const float4*)sS)[sid];
          float e0 = __expf(lrelu(db0 + sv.x));
          float e1 = __expf(lrelu(db1 + sv.y));
          float e2 = __expf(lrelu(db2 + sv.z));
          float e3 = __expf(lrelu(db3 + sv.w));
          z0 += e0; z1 += e1; z2 += e2; z3 += e3;
          sidbuf[wv][lane] = sid;
          *(float4*)&exbuf[wv][lane * 4] = make_float4(e0, e1, e2, e3);
        }
        int q = 0;
        for (; q + 2 <= cnt; q += 2) {
          int s0 = sb[q], s1 = sb[q + 1];
          float w0 = eb[q * 4], w1 = eb[q * 4 + 4];
          float f0 = __uint_as_float(((unsigned)Whb2[(((size_t)s0) << 6) + lane]) << 16);
          float f1 = __uint_as_float(((unsigned)Whb2[(((size_t)s1) << 6) + lane]) << 16);
          acc = fmaf(w0, f0, acc);
          acc = fmaf(w1, f1, acc);
        }
        if (q < cnt) {
          int s0 = sb[q];
          float w0 = eb[q * 4];
          float f0 = __uint_as_float(((unsigned)Whb2[(((size_t)s0) << 6) + lane]) << 16);
          acc = fmaf(w0, f0, acc);
        }
      }
      #pragma unroll
      for (int s = 32; s; s >>= 1) {
        z0 += __shfl_xor(z0, s);
        z1 += __shfl_xor(z1, s);
        z2 += __shfl_xor(z2, s);
        z3 += __shfl_xor(z3, s);
      }
      float zh = (h == 0) ? z0 : (h == 1) ? z1 : (h == 2) ? z2 : z3;
      val = acc / zh;
    }
    val += __shfl_xor(val, 16);
    val += __shfl_xor(val, 32);
    val *= 0.25f;
    float mx = val;
    #pragma unroll
    for (int s = 8; s; s >>= 1) mx = fmaxf(mx, __shfl_xor(mx, s));
    float ev = __expf(val - mx);
    float ssum = ev;
    #pragma unroll
    for (int s = 8; s; s >>= 1) ssum += __shfl_xor(ssum, s);
    p = ev / ssum;
  }
  if (lane < 16) red[wv][lane] = active ? p : 0.f;
  __syncthreads();
  if (threadIdx.x < 16) {
    partials[(size_t)blockIdx.x * 16 + threadIdx.x] =
        red[0][threadIdx.x] + red[1][threadIdx.x] +
        red[2][threadIdx.x] + red[3][threadIdx.x];
  }
}

// ============== hierarchical final reduce: 25000 -> 128 -> fc ==============
__global__ __launch_bounds__(256)
void k_reduce1(const float* __restrict__ partials, int nrows,
               float* __restrict__ out) {
  __shared__ float red[16][17];
  int t = threadIdx.x;
  int c = t & 15, rl = t >> 4;
  int per = (nrows + RB1 - 1) / RB1;
  int rbeg = blockIdx.x * per;
  int rend = rbeg + per; if (rend > nrows) rend = nrows;
  float s = 0.f;
  for (int r = rbeg + rl; r < rend; r += 16) s += partials[(size_t)r * 16 + c];
  red[rl][c] = s;
  __syncthreads();
  for (int st = 8; st; st >>= 1) {
    if (rl < st) red[rl][c] += red[rl + st][c];
    __syncthreads();
  }
  if (t < 16) out[(size_t)blockIdx.x * 16 + t] = red[0][t];
}

__global__ __launch_bounds__(256)
void k_final(const float* __restrict__ partials,
             const float* __restrict__ fcw, const float* __restrict__ fcb,
             float* __restrict__ out) {
  __shared__ float red[16][17];
  __shared__ float hg[16];
  int t = threadIdx.x;
  int c = t & 15, rl = t >> 4;
  float s = 0.f;
  for (int r = rl; r < RB1; r += 16) s += partials[(size_t)r * 16 + c];
  red[rl][c] = s;
  __syncthreads();
  for (int st = 8; st; st >>= 1) {
    if (rl < st) red[rl][c] += red[rl + st][c];
    __syncthreads();
  }
  if (t < 16) hg[t] = red[0][t] * (1.0f / N_NODES);
  __syncthreads();
  if (t < 16) {
    float acc = fcb[t];
    #pragma unroll
    for (int k = 0; k < 16; ++k) acc += hg[k] * fcw[t * 16 + k];
    out[t] = acc;
  }
}

// ============================ launcher ============================
extern "C" void kernel_launch(void* const* d_in, const int* in_sizes, int n_in,
                              void* d_out, int out_size, void* d_ws, size_t ws_size,
                              hipStream_t stream) {
  const float* h   = (const float*)d_in[0];
  const int*   src = (const int*)  d_in[1];
  const int*   dst = (const int*)  d_in[2];
  const float* W1  = (const float*)d_in[3];
  const float* b1  = (const float*)d_in[4];
  const float* a1  = (const float*)d_in[5];
  const float* ab1 = (const float*)d_in[6];
  const float* W2  = (const float*)d_in[7];
  const float* b2  = (const float*)d_in[8];
  const float* a2  = (const float*)d_in[9];
  const float* ab2 = (const float*)d_in[10];
  const float* fcw = (const float*)d_in[11];
  const float* fcb = (const float*)d_in[12];
  float* out = (float*)d_out;

  char* ws = (char*)d_ws;
  size_t off = 0;
  auto alloc = [&](size_t bytes) -> char* {
    char* p = ws + off;
    off += (bytes + 255) & ~(size_t)255;
    return p;
  };
  unsigned short* Whb1 = (unsigned short*)alloc((size_t)N_NODES * D1 * 2); // 51.2 MB
  unsigned short* h1b  = (unsigned short*)alloc((size_t)N_NODES * D1 * 2); // 51.2 MB
  unsigned short* Whb2 = (unsigned short*)alloc((size_t)N_NODES * D2 * 2); // 12.8 MB
  float* sD1 = (float*)alloc((size_t)N_NODES * 4 * 4);
  float* sS1 = (float*)alloc((size_t)N_NODES * 4 * 4);
  float* sD2 = (float*)alloc((size_t)N_NODES * 4 * 4);
  float* sS2 = (float*)alloc((size_t)N_NODES * 4 * 4);
  int* cursorPad = (int*)alloc((size_t)N_NODES * 16 * 4);   // 6.4 MB, 1 counter / 64B line
  int* rank   = (int*)alloc((size_t)N_EDGES * 4);           // 6.4 MB
  int* counts = (int*)alloc((size_t)N_NODES_PAD * 4);
  int* offs   = (int*)alloc((size_t)(N_NODES + 1) * 4);
  int* csrsrc = (int*)alloc((size_t)N_EDGES * 4);
  int* btot   = (int*)alloc((size_t)SCAN_NB * 4);
  int* bbase  = (int*)alloc((size_t)SCAN_NB * 4);
  const int nblk_node = (N_NODES + 3) / 4;   // 25000
  float* partials  = (float*)alloc((size_t)nblk_node * 16 * 4);
  float* partials2 = (float*)alloc((size_t)RB1 * 16 * 4);

  // --- CSR build (by dst); atomic-free scatter via fetch-add rank ---
  const int n4 = N_NODES * 4;   // 400k int4 = 6.4 MB
  k_zero4<<<(n4 + 255) / 256, 256, 0, stream>>>((int4*)cursorPad, n4);
  k_count<<<(N_EDGES + 255) / 256, 256, 0, stream>>>(dst, cursorPad, rank);
  k_compact<<<(N_NODES_PAD + 255) / 256, 256, 0, stream>>>(cursorPad, counts);
  k_scanA<<<SCAN_NB, 256, 0, stream>>>(counts, btot);
  k_scanB<<<1, 128, 0, stream>>>(btot, bbase, offs);
  k_scanC<<<SCAN_NB, 256, 0, stream>>>(counts, bbase, offs);
  k_scatter<<<(N_EDGES + 255) / 256, 256, 0, stream>>>(src, dst, rank, offs, csrsrc);

  // --- layer 1 ---
  k_gemm1<<<dim3((N_NODES + 127) / 128, 2), 256, 0, stream>>>(h, W1, b1, Whb1);
  k_scores1<<<nblk_node, 256, 0, stream>>>(Whb1, a1, sD1, sS1);
  k_agg1<<<nblk_node, 256, 0, stream>>>(offs, csrsrc, sD1, sS1, ab1, Whb1, h1b);

  // --- layer 2 ---
  k_gemm2<<<dim3((N_NODES + 127) / 128, 1), 256, 0, stream>>>(h1b, W2, b2, Whb2);
  k_scores2<<<nblk_node, 256, 0, stream>>>(Whb2, a2, sD2, sS2);
  k_agg2<<<nblk_node, 256, 0, stream>>>(offs, csrsrc, sD2, sS2, ab2, Whb2, partials);

  // --- readout ---
  k_reduce1<<<RB1, 256, 0, stream>>>(partials, nblk_node, partials2);
  k_final<<<1, 256, 0, stream>>>(partials2, fcw, fcb, out);
}

// Round 6
// 586.532 us; speedup vs baseline: 2.5455x; 1.0759x over previous
//
#include <hip/hip_runtime.h>
#include <math.h>

#define N_NODES  100000
#define N_EDGES  1600000
#define IN_F     128
#define HID      64
#define HEADS    4
#define NCLS     16
#define D1       (HEADS*HID)    // 256
#define D2       (HEADS*NCLS)   // 64

#define SCAN_CHUNK 1024
#define SCAN_NB    ((N_NODES + SCAN_CHUNK - 1) / SCAN_CHUNK)   // 98
#define N_NODES_PAD (SCAN_NB * SCAN_CHUNK)                     // 100352
#define RB1 128   // reduce-stage-1 blocks

typedef __attribute__((ext_vector_type(8))) short bf16x8_t;
typedef __attribute__((ext_vector_type(4))) float f32x4_t;

// bf16 helpers (RNE)
__device__ __forceinline__ unsigned bf16rne(float x) {
  unsigned u = __float_as_uint(x);
  return (u + 0x7fffu + ((u >> 16) & 1u)) >> 16;
}
__device__ __forceinline__ unsigned packbf2(float lo, float hi) {
  return bf16rne(lo) | (bf16rne(hi) << 16);
}
__device__ __forceinline__ float bflo(unsigned p) { return __uint_as_float(p << 16); }
__device__ __forceinline__ float bfhi(unsigned p) { return __uint_as_float(p & 0xffff0000u); }

// ============================ CSR build ============================
__global__ __launch_bounds__(256)
void k_zero4(int4* __restrict__ p, int n4) {
  int i = blockIdx.x * blockDim.x + threadIdx.x;
  if (i < n4) p[i] = make_int4(0, 0, 0, 0);
}

// count + per-edge rank (atomic return), rank stored coalesced
__global__ __launch_bounds__(256)
void k_count(const int* __restrict__ dst, int* __restrict__ cursorPad,
             int* __restrict__ rank) {
  int i = blockIdx.x * blockDim.x + threadIdx.x;
  if (i < N_EDGES) {
    int d = dst[i];
    rank[i] = atomicAdd(&cursorPad[d << 4], 1);
  }
}

__global__ __launch_bounds__(256)
void k_compact(const int* __restrict__ cursorPad, int* __restrict__ counts) {
  int i = blockIdx.x * blockDim.x + threadIdx.x;
  if (i < N_NODES_PAD) counts[i] = (i < N_NODES) ? cursorPad[i << 4] : 0;
}

__global__ __launch_bounds__(256)
void k_scanA(const int* __restrict__ counts, int* __restrict__ btot) {
  __shared__ int red[256];
  int t = threadIdx.x;
  const int4* cp = (const int4*)(counts + blockIdx.x * SCAN_CHUNK);
  int4 v = cp[t];
  red[t] = v.x + v.y + v.z + v.w;
  __syncthreads();
  for (int s = 128; s; s >>= 1) {
    if (t < s) red[t] += red[t + s];
    __syncthreads();
  }
  if (t == 0) btot[blockIdx.x] = red[0];
}

__global__ __launch_bounds__(128)
void k_scanB(const int* __restrict__ btot, int* __restrict__ bbase,
             int* __restrict__ offs) {
  __shared__ int part[128];
  int t = threadIdx.x;
  part[t] = (t < SCAN_NB) ? btot[t] : 0;
  __syncthreads();
  for (int o = 1; o < 128; o <<= 1) {
    int v = (t >= o) ? part[t - o] : 0;
    __syncthreads();
    part[t] += v;
    __syncthreads();
  }
  if (t < SCAN_NB) bbase[t] = (t == 0) ? 0 : part[t - 1];
  if (t == 0) offs[N_NODES] = N_EDGES;
}

__global__ __launch_bounds__(256)
void k_scanC(const int* __restrict__ counts, const int* __restrict__ bbase,
             int* __restrict__ offs) {
  __shared__ int part[256];
  int t = threadIdx.x;
  int gbase = blockIdx.x * SCAN_CHUNK;
  const int4* cp = (const int4*)(counts + gbase);
  int4 v = cp[t];
  int tot = v.x + v.y + v.z + v.w;
  part[t] = tot;
  __syncthreads();
  for (int o = 1; o < 256; o <<= 1) {
    int q = (t >= o) ? part[t - o] : 0;
    __syncthreads();
    part[t] += q;
    __syncthreads();
  }
  int run = bbase[blockIdx.x] + part[t] - tot;
  int i0 = gbase + t * 4;
  int o0 = run;
  int o1 = o0 + v.x;
  int o2 = o1 + v.y;
  int o3 = o2 + v.z;
  if (i0 + 0 < N_NODES) offs[i0 + 0] = o0;
  if (i0 + 1 < N_NODES) offs[i0 + 1] = o1;
  if (i0 + 2 < N_NODES) offs[i0 + 2] = o2;
  if (i0 + 3 < N_NODES) offs[i0 + 3] = o3;
}

// atomic-free scatter: pos = offs[dst] + rank; fire-and-forget store
__global__ __launch_bounds__(256)
void k_scatter(const int* __restrict__ src, const int* __restrict__ dst,
               const int* __restrict__ rank, const int* __restrict__ offs,
               int* __restrict__ csrsrc) {
  int i = blockIdx.x * blockDim.x + threadIdx.x;
  if (i < N_EDGES) {
    csrsrc[offs[dst[i]] + rank[i]] = src[i];
  }
}

// ============== weight transpose to k-contiguous bf16 ==============
// W1t[c][f]: c=h*64+o (256 rows), f 0..127;  W2t[c][f]: c=h*16+o (64 rows), f 0..255
__global__ __launch_bounds__(256)
void k_prepw(const float* __restrict__ W1, const float* __restrict__ W2,
             unsigned* __restrict__ W1t32, unsigned* __restrict__ W2t32) {
  int t = threadIdx.x;
  if (blockIdx.x == 0) {
    int c = t;
    const float* wp = W1 + ((c >> 6) << 13) + (c & 63);
    unsigned* op = W1t32 + c * 64;
    for (int fp = 0; fp < 64; ++fp) {
      float lo = wp[(2 * fp) << 6];
      float hi = wp[(2 * fp + 1) << 6];
      op[fp] = packbf2(lo, hi);
    }
  } else {
    int c = t & 63, fq = t >> 6;   // 4 f-quarters
    const float* wp = W2 + ((c >> 4) << 12) + (c & 15);
    unsigned* op = W2t32 + c * 128 + fq * 32;
    for (int fp = 0; fp < 32; ++fp) {
      int f0 = fq * 64 + 2 * fp;
      op[fp] = packbf2(wp[f0 << 4], wp[(f0 + 1) << 4]);
    }
  }
}

// ============================ GEMM 1 (MFMA) ============================
// Whb[n][256](bf16) = h[n][128](f32->bf16) x W1t^T (+b1)
// mfma 16x16x32: m=c (A=W1t rows), n=node (B=h rows), k=f
__global__ __launch_bounds__(256)
void k_gemm1(const float* __restrict__ h, const unsigned short* __restrict__ W1t,
             const float* __restrict__ bias, unsigned short* __restrict__ Whb) {
  int wv = threadIdx.x >> 6;
  int lane = threadIdx.x & 63;
  int m = lane & 15;            // A-row (c) / B-row (node) selector
  int q8 = (lane >> 4) * 8;     // k-offset within 32-wide step
  int node = blockIdx.x * 64 + wv * 16 + m;
  int nclamp = node < N_NODES ? node : N_NODES - 1;

  f32x4_t acc[16] = {};
  const float* hp0 = h + (size_t)nclamp * IN_F + q8;
  #pragma unroll
  for (int ks = 0; ks < 4; ++ks) {
    int kk = ks * 32;
    float4 f0 = *(const float4*)(hp0 + kk);
    float4 f1 = *(const float4*)(hp0 + kk + 4);
    bf16x8_t bf;
    bf[0] = (short)bf16rne(f0.x); bf[1] = (short)bf16rne(f0.y);
    bf[2] = (short)bf16rne(f0.z); bf[3] = (short)bf16rne(f0.w);
    bf[4] = (short)bf16rne(f1.x); bf[5] = (short)bf16rne(f1.y);
    bf[6] = (short)bf16rne(f1.z); bf[7] = (short)bf16rne(f1.w);
    #pragma unroll
    for (int ct = 0; ct < 16; ++ct) {
      bf16x8_t af = *(const bf16x8_t*)(W1t + (ct * 16 + m) * IN_F + kk + q8);
      acc[ct] = __builtin_amdgcn_mfma_f32_16x16x32_bf16(af, bf, acc[ct], 0, 0, 0);
    }
  }
  if (node < N_NODES) {
    unsigned short* op = Whb + (size_t)node * D1;
    int quad4 = (lane >> 4) * 4;
    #pragma unroll
    for (int ct = 0; ct < 16; ++ct) {
      int c0 = ct * 16 + quad4;
      float4 bb = *(const float4*)(bias + c0);
      uint2 o;
      o.x = packbf2(acc[ct][0] + bb.x, acc[ct][1] + bb.y);
      o.y = packbf2(acc[ct][2] + bb.z, acc[ct][3] + bb.w);
      *(uint2*)(op + c0) = o;
    }
  }
}

// ============================ GEMM 2 (MFMA) ============================
// Whb2[n][64](bf16) = h1b[n][256](bf16) x W2t^T (+b2)
__global__ __launch_bounds__(256)
void k_gemm2(const unsigned short* __restrict__ h1b, const unsigned short* __restrict__ W2t,
             const float* __restrict__ bias, unsigned short* __restrict__ Whb2) {
  int wv = threadIdx.x >> 6;
  int lane = threadIdx.x & 63;
  int m = lane & 15;
  int q8 = (lane >> 4) * 8;
  int node = blockIdx.x * 64 + wv * 16 + m;
  int nclamp = node < N_NODES ? node : N_NODES - 1;

  f32x4_t acc[4] = {};
  const unsigned short* hp0 = h1b + (size_t)nclamp * D1 + q8;
  #pragma unroll
  for (int ks = 0; ks < 8; ++ks) {
    int kk = ks * 32;
    bf16x8_t bf = *(const bf16x8_t*)(hp0 + kk);
    #pragma unroll
    for (int ct = 0; ct < 4; ++ct) {
      bf16x8_t af = *(const bf16x8_t*)(W2t + (ct * 16 + m) * D1 + kk + q8);
      acc[ct] = __builtin_amdgcn_mfma_f32_16x16x32_bf16(af, bf, acc[ct], 0, 0, 0);
    }
  }
  if (node < N_NODES) {
    unsigned short* op = Whb2 + (size_t)node * D2;
    int quad4 = (lane >> 4) * 4;
    #pragma unroll
    for (int ct = 0; ct < 4; ++ct) {
      int c0 = ct * 16 + quad4;
      float4 bb = *(const float4*)(bias + c0);
      uint2 o;
      o.x = packbf2(acc[ct][0] + bb.x, acc[ct][1] + bb.y);
      o.y = packbf2(acc[ct][2] + bb.z, acc[ct][3] + bb.w);
      *(uint2*)(op + c0) = o;
    }
  }
}

// ============================ per-node scores ============================
__global__ __launch_bounds__(256)
void k_scores1(const unsigned short* __restrict__ Whb, const float* __restrict__ a,
               float* __restrict__ sD, float* __restrict__ sS) {
  int wid = (blockIdx.x * blockDim.x + threadIdx.x) >> 6;
  int lane = threadIdx.x & 63;
  if (wid >= N_NODES) return;
  int h = lane >> 4;
  uint2 p = *(const uint2*)(Whb + (size_t)wid * D1 + lane * 4);
  float f0 = bflo(p.x), f1 = bfhi(p.x), f2 = bflo(p.y), f3 = bfhi(p.y);
  int o0 = (lane & 15) * 4;
  const float* ah = a + h * 128;
  float pd = f0 * ah[o0] + f1 * ah[o0 + 1] + f2 * ah[o0 + 2] + f3 * ah[o0 + 3];
  float ps = f0 * ah[64 + o0] + f1 * ah[64 + o0 + 1] + f2 * ah[64 + o0 + 2] + f3 * ah[64 + o0 + 3];
  #pragma unroll
  for (int s = 8; s; s >>= 1) {
    pd += __shfl_xor(pd, s);
    ps += __shfl_xor(ps, s);
  }
  float4 dv = make_float4(__shfl(pd, 0), __shfl(pd, 16), __shfl(pd, 32), __shfl(pd, 48));
  float4 sv = make_float4(__shfl(ps, 0), __shfl(ps, 16), __shfl(ps, 32), __shfl(ps, 48));
  if (lane == 0) {
    ((float4*)sD)[wid] = dv;
    ((float4*)sS)[wid] = sv;
  }
}

__global__ __launch_bounds__(256)
void k_scores2(const unsigned short* __restrict__ Whb2, const float* __restrict__ a,
               float* __restrict__ sD, float* __restrict__ sS) {
  int wid = (blockIdx.x * blockDim.x + threadIdx.x) >> 6;
  int lane = threadIdx.x & 63;
  if (wid >= N_NODES) return;
  int h = lane >> 4, o = lane & 15;
  float w = __uint_as_float(((unsigned)Whb2[(size_t)wid * D2 + lane]) << 16);
  float pd = w * a[h * 32 + o];
  float ps = w * a[h * 32 + 16 + o];
  #pragma unroll
  for (int s = 8; s; s >>= 1) {
    pd += __shfl_xor(pd, s);
    ps += __shfl_xor(ps, s);
  }
  if (o == 0) {
    sD[wid * 4 + h] = pd;
    sS[wid * 4 + h] = ps;
  }
}

// ============================ layer-1 aggregate ============================
__device__ __forceinline__ float lrelu(float x) { return x > 0.f ? x : 0.2f * x; }
__device__ __forceinline__ float elu(float x)   { return x > 0.f ? x : expm1f(x); }

// one wave per node; single pass (no max subtraction), LDS-staged edge weights
__global__ __launch_bounds__(256)
void k_agg1(const int* __restrict__ offs, const int* __restrict__ csrsrc,
            const float* __restrict__ sD, const float* __restrict__ sS,
            const float* __restrict__ ab,
            const unsigned short* __restrict__ Whb, unsigned short* __restrict__ h1out) {
  __shared__ float exbuf[4][64 * 4];
  __shared__ int   sidbuf[4][64];
  int wv = threadIdx.x >> 6;
  int wid = blockIdx.x * 4 + wv;
  int lane = threadIdx.x & 63;
  if (wid >= N_NODES) return;
  int h = lane >> 4;
  int beg = offs[wid], end = offs[wid + 1];
  float a0 = 0.f, a1v = 0.f, a2v = 0.f, a3v = 0.f;   // feats 4*lane..4*lane+3
  float z = 1.f;
  if (end > beg) {
    float4 dv = ((const float4*)sD)[wid];
    float db0 = dv.x + ab[0], db1 = dv.y + ab[1];
    float db2 = dv.z + ab[2], db3 = dv.w + ab[3];
    float z0 = 0.f, z1 = 0.f, z2 = 0.f, z3 = 0.f;
    const int* sb = sidbuf[wv];
    const float* eb = &exbuf[wv][h];
    for (int cbeg = beg; cbeg < end; cbeg += 64) {
      int j = cbeg + lane;
      int cnt = end - cbeg; if (cnt > 64) cnt = 64;
      if (j < end) {
        int sid = csrsrc[j];
        float4 sv = ((const float4*)sS)[sid];
        float e0 = __expf(lrelu(db0 + sv.x));
        float e1 = __expf(lrelu(db1 + sv.y));
        float e2 = __expf(lrelu(db2 + sv.z));
        float e3 = __expf(lrelu(db3 + sv.w));
        z0 += e0; z1 += e1; z2 += e2; z3 += e3;
        sidbuf[wv][lane] = sid;
        *(float4*)&exbuf[wv][lane * 4] = make_float4(e0, e1, e2, e3);
      }
      int q = 0;
      for (; q + 2 <= cnt; q += 2) {
        int s0 = sb[q], s1 = sb[q + 1];
        float w0 = eb[q * 4], w1 = eb[q * 4 + 4];
        uint2 p0 = *(const uint2*)(Whb + (((size_t)s0) << 8) + (lane << 2));
        uint2 p1 = *(const uint2*)(Whb + (((size_t)s1) << 8) + (lane << 2));
        a0  = fmaf(w0, __uint_as_float(p0.x << 16), a0);
        a1v = fmaf(w0, __uint_as_float(p0.x), a1v);
        a2v = fmaf(w0, __uint_as_float(p0.y << 16), a2v);
        a3v = fmaf(w0, __uint_as_float(p0.y), a3v);
        a0  = fmaf(w1, __uint_as_float(p1.x << 16), a0);
        a1v = fmaf(w1, __uint_as_float(p1.x), a1v);
        a2v = fmaf(w1, __uint_as_float(p1.y << 16), a2v);
        a3v = fmaf(w1, __uint_as_float(p1.y), a3v);
      }
      if (q < cnt) {
        int s0 = sb[q];
        float w0 = eb[q * 4];
        uint2 p0 = *(const uint2*)(Whb + (((size_t)s0) << 8) + (lane << 2));
        a0  = fmaf(w0, __uint_as_float(p0.x << 16), a0);
        a1v = fmaf(w0, __uint_as_float(p0.x), a1v);
        a2v = fmaf(w0, __uint_as_float(p0.y << 16), a2v);
        a3v = fmaf(w0, __uint_as_float(p0.y), a3v);
      }
    }
    #pragma unroll
    for (int o = 32; o; o >>= 1) {
      z0 += __shfl_xor(z0, o);
      z1 += __shfl_xor(z1, o);
      z2 += __shfl_xor(z2, o);
      z3 += __shfl_xor(z3, o);
    }
    z = (h == 0) ? z0 : (h == 1) ? z1 : (h == 2) ? z2 : z3;
  }
  float o0 = elu(a0 / z), o1 = elu(a1v / z), o2 = elu(a2v / z), o3 = elu(a3v / z);
  uint2 o;
  o.x = packbf2(o0, o1);
  o.y = packbf2(o2, o3);
  *(uint2*)(h1out + (size_t)wid * D1 + lane * 4) = o;
}

// ============================ layer-2 aggregate + softmax + partial mean ====
__global__ __launch_bounds__(256)
void k_agg2(const int* __restrict__ offs, const int* __restrict__ csrsrc,
            const float* __restrict__ sD, const float* __restrict__ sS,
            const float* __restrict__ ab,
            const unsigned short* __restrict__ Whb2, float* __restrict__ partials) {
  __shared__ float exbuf[4][64 * 4];
  __shared__ int   sidbuf[4][64];
  __shared__ float red[4][16];
  int wv = threadIdx.x >> 6;
  int wid = blockIdx.x * 4 + wv;
  int lane = threadIdx.x & 63;
  int h = lane >> 4, o = lane & 15;
  float p = 0.f;
  bool active = wid < N_NODES;
  if (active) {
    float val = 0.f;
    int beg = offs[wid], end = offs[wid + 1];
    if (end > beg) {
      float4 dv = ((const float4*)sD)[wid];
      float db0 = dv.x + ab[0], db1 = dv.y + ab[1];
      float db2 = dv.z + ab[2], db3 = dv.w + ab[3];
      float acc = 0.f;
      float z0 = 0.f, z1 = 0.f, z2 = 0.f, z3 = 0.f;
      const int* sb = sidbuf[wv];
      const float* eb = &exbuf[wv][h];
      for (int cbeg = beg; cbeg < end; cbeg += 64) {
        int j = cbeg + lane;
        int cnt = end - cbeg; if (cnt > 64) cnt = 64;
        if (j < end) {
          int sid = csrsrc[j];
          float4 sv = ((const float4*)sS)[sid];
          float e0 = __expf(lrelu(db0 + sv.x));
          float e1 = __expf(lrelu(db1 + sv.y));
          float e2 = __expf(lrelu(db2 + sv.z));
          float e3 = __expf(lrelu(db3 + sv.w));
          z0 += e0; z1 += e1; z2 += e2; z3 += e3;
          sidbuf[wv][lane] = sid;
          *(float4*)&exbuf[wv][lane * 4] = make_float4(e0, e1, e2, e3);
        }
        int q = 0;
        for (; q + 2 <= cnt; q += 2) {
          int s0 = sb[q], s1 = sb[q + 1];
          float w0 = eb[q * 4], w1 = eb[q * 4 + 4];
          float f0 = __uint_as_float(((unsigned)Whb2[(((size_t)s0) << 6) + lane]) << 16);
          float f1 = __uint_as_float(((unsigned)Whb2[(((size_t)s1) << 6) + lane]) << 16);
          acc = fmaf(w0, f0, acc);
          acc = fmaf(w1, f1, acc);
        }
        if (q < cnt) {
          int s0 = sb[q];
          float w0 = eb[q * 4];
          float f0 = __uint_as_float(((unsigned)Whb2[(((size_t)s0) << 6) + lane]) << 16);
          acc = fmaf(w0, f0, acc);
        }
      }
      #pragma unroll
      for (int s = 32; s; s >>= 1) {
        z0 += __shfl_xor(z0, s);
        z1 += __shfl_xor(z1, s);
        z2 += __shfl_xor(z2, s);
        z3 += __shfl_xor(z3, s);
      }
      float zh = (h == 0) ? z0 : (h == 1) ? z1 : (h == 2) ? z2 : z3;
      val = acc / zh;
    }
    val += __shfl_xor(val, 16);
    val += __shfl_xor(val, 32);
    val *= 0.25f;
    float mx = val;
    #pragma unroll
    for (int s = 8; s; s >>= 1) mx = fmaxf(mx, __shfl_xor(mx, s));
    float ev = __expf(val - mx);
    float ssum = ev;
    #pragma unroll
    for (int s = 8; s; s >>= 1) ssum += __shfl_xor(ssum, s);
    p = ev / ssum;
  }
  if (lane < 16) red[wv][lane] = active ? p : 0.f;
  __syncthreads();
  if (threadIdx.x < 16) {
    partials[(size_t)blockIdx.x * 16 + threadIdx.x] =
        red[0][threadIdx.x] + red[1][threadIdx.x] +
        red[2][threadIdx.x] + red[3][threadIdx.x];
  }
}

// ============== hierarchical final reduce: 25000 -> 128 -> fc ==============
__global__ __launch_bounds__(256)
void k_reduce1(const float* __restrict__ partials, int nrows,
               float* __restrict__ out) {
  __shared__ float red[16][17];
  int t = threadIdx.x;
  int c = t & 15, rl = t >> 4;
  int per = (nrows + RB1 - 1) / RB1;
  int rbeg = blockIdx.x * per;
  int rend = rbeg + per; if (rend > nrows) rend = nrows;
  float s = 0.f;
  for (int r = rbeg + rl; r < rend; r += 16) s += partials[(size_t)r * 16 + c];
  red[rl][c] = s;
  __syncthreads();
  for (int st = 8; st; st >>= 1) {
    if (rl < st) red[rl][c] += red[rl + st][c];
    __syncthreads();
  }
  if (t < 16) out[(size_t)blockIdx.x * 16 + t] = red[0][t];
}

__global__ __launch_bounds__(256)
void k_final(const float* __restrict__ partials,
             const float* __restrict__ fcw, const float* __restrict__ fcb,
             float* __restrict__ out) {
  __shared__ float red[16][17];
  __shared__ float hg[16];
  int t = threadIdx.x;
  int c = t & 15, rl = t >> 4;
  float s = 0.f;
  for (int r = rl; r < RB1; r += 16) s += partials[(size_t)r * 16 + c];
  red[rl][c] = s;
  __syncthreads();
  for (int st = 8; st; st >>= 1) {
    if (rl < st) red[rl][c] += red[rl + st][c];
    __syncthreads();
  }
  if (t < 16) hg[t] = red[0][t] * (1.0f / N_NODES);
  __syncthreads();
  if (t < 16) {
    float acc = fcb[t];
    #pragma unroll
    for (int k = 0; k < 16; ++k) acc += hg[k] * fcw[t * 16 + k];
    out[t] = acc;
  }
}

// ============================ launcher ============================
extern "C" void kernel_launch(void* const* d_in, const int* in_sizes, int n_in,
                              void* d_out, int out_size, void* d_ws, size_t ws_size,
                              hipStream_t stream) {
  const float* h   = (const float*)d_in[0];
  const int*   src = (const int*)  d_in[1];
  const int*   dst = (const int*)  d_in[2];
  const float* W1  = (const float*)d_in[3];
  const float* b1  = (const float*)d_in[4];
  const float* a1  = (const float*)d_in[5];
  const float* ab1 = (const float*)d_in[6];
  const float* W2  = (const float*)d_in[7];
  const float* b2  = (const float*)d_in[8];
  const float* a2  = (const float*)d_in[9];
  const float* ab2 = (const float*)d_in[10];
  const float* fcw = (const float*)d_in[11];
  const float* fcb = (const float*)d_in[12];
  float* out = (float*)d_out;

  char* ws = (char*)d_ws;
  size_t off = 0;
  auto alloc = [&](size_t bytes) -> char* {
    char* p = ws + off;
    off += (bytes + 255) & ~(size_t)255;
    return p;
  };
  unsigned short* Whb1 = (unsigned short*)alloc((size_t)N_NODES * D1 * 2); // 51.2 MB
  unsigned short* h1b  = (unsigned short*)alloc((size_t)N_NODES * D1 * 2); // 51.2 MB
  unsigned short* Whb2 = (unsigned short*)alloc((size_t)N_NODES * D2 * 2); // 12.8 MB
  unsigned short* W1t  = (unsigned short*)alloc((size_t)D1 * IN_F * 2);    // 64 KB
  unsigned short* W2t  = (unsigned short*)alloc((size_t)D2 * D1 * 2);      // 32 KB
  float* sD1 = (float*)alloc((size_t)N_NODES * 4 * 4);
  float* sS1 = (float*)alloc((size_t)N_NODES * 4 * 4);
  float* sD2 = (float*)alloc((size_t)N_NODES * 4 * 4);
  float* sS2 = (float*)alloc((size_t)N_NODES * 4 * 4);
  int* cursorPad = (int*)alloc((size_t)N_NODES * 16 * 4);   // 6.4 MB
  int* rank   = (int*)alloc((size_t)N_EDGES * 4);           // 6.4 MB
  int* counts = (int*)alloc((size_t)N_NODES_PAD * 4);
  int* offs   = (int*)alloc((size_t)(N_NODES + 1) * 4);
  int* csrsrc = (int*)alloc((size_t)N_EDGES * 4);
  int* btot   = (int*)alloc((size_t)SCAN_NB * 4);
  int* bbase  = (int*)alloc((size_t)SCAN_NB * 4);
  const int nblk_node = (N_NODES + 3) / 4;   // 25000
  float* partials  = (float*)alloc((size_t)nblk_node * 16 * 4);
  float* partials2 = (float*)alloc((size_t)RB1 * 16 * 4);

  // --- weight transpose (bf16, k-contiguous) ---
  k_prepw<<<2, 256, 0, stream>>>(W1, W2, (unsigned*)W1t, (unsigned*)W2t);

  // --- CSR build (by dst); atomic-free scatter via fetch-add rank ---
  const int n4 = N_NODES * 4;
  k_zero4<<<(n4 + 255) / 256, 256, 0, stream>>>((int4*)cursorPad, n4);
  k_count<<<(N_EDGES + 255) / 256, 256, 0, stream>>>(dst, cursorPad, rank);
  k_compact<<<(N_NODES_PAD + 255) / 256, 256, 0, stream>>>(cursorPad, counts);
  k_scanA<<<SCAN_NB, 256, 0, stream>>>(counts, btot);
  k_scanB<<<1, 128, 0, stream>>>(btot, bbase, offs);
  k_scanC<<<SCAN_NB, 256, 0, stream>>>(counts, bbase, offs);
  k_scatter<<<(N_EDGES + 255) / 256, 256, 0, stream>>>(src, dst, rank, offs, csrsrc);

  const int gemmBlocks = (N_NODES + 63) / 64;   // 1563

  // --- layer 1 ---
  k_gemm1<<<gemmBlocks, 256, 0, stream>>>(h, W1t, b1, Whb1);
  k_scores1<<<nblk_node, 256, 0, stream>>>(Whb1, a1, sD1, sS1);
  k_agg1<<<nblk_node, 256, 0, stream>>>(offs, csrsrc, sD1, sS1, ab1, Whb1, h1b);

  // --- layer 2 ---
  k_gemm2<<<gemmBlocks, 256, 0, stream>>>(h1b, W2t, b2, Whb2);
  k_scores2<<<nblk_node, 256, 0, stream>>>(Whb2, a2, sD2, sS2);
  k_agg2<<<nblk_node, 256, 0, stream>>>(offs, csrsrc, sD2, sS2, ab2, Whb2, partials);

  // --- readout ---
  k_reduce1<<<RB1, 256, 0, stream>>>(partials, nblk_node, partials2);
  k_final<<<1, 256, 0, stream>>>(partials2, fcw, fcb, out);
}

// Round 7
// 519.349 us; speedup vs baseline: 2.8748x; 1.1294x over previous
//
#include <hip/hip_runtime.h>
#include <math.h>

#define N_NODES  100000
#define N_EDGES  1600000
#define IN_F     128
#define HID      64
#define HEADS    4
#define NCLS     16
#define D1       (HEADS*HID)    // 256
#define D2       (HEADS*NCLS)   // 64

#define SCAN_CHUNK 1024
#define SCAN_NB    ((N_NODES + SCAN_CHUNK - 1) / SCAN_CHUNK)   // 98
#define N_NODES_PAD (SCAN_NB * SCAN_CHUNK)                     // 100352
#define RB1 128   // reduce-stage-1 blocks

typedef __attribute__((ext_vector_type(8))) short bf16x8_t;
typedef __attribute__((ext_vector_type(4))) float f32x4_t;

// bf16 helpers (RNE)
__device__ __forceinline__ unsigned bf16rne(float x) {
  unsigned u = __float_as_uint(x);
  return (u + 0x7fffu + ((u >> 16) & 1u)) >> 16;
}
__device__ __forceinline__ unsigned packbf2(float lo, float hi) {
  return bf16rne(lo) | (bf16rne(hi) << 16);
}
__device__ __forceinline__ float bflo(unsigned p) { return __uint_as_float(p << 16); }
__device__ __forceinline__ float bfhi(unsigned p) { return __uint_as_float(p & 0xffff0000u); }

// ============================ CSR build ============================
__global__ __launch_bounds__(256)
void k_zero4(int4* __restrict__ p, int n4) {
  int i = blockIdx.x * blockDim.x + threadIdx.x;
  if (i < n4) p[i] = make_int4(0, 0, 0, 0);
}

__global__ __launch_bounds__(256)
void k_count(const int* __restrict__ dst, int* __restrict__ cursorPad,
             int* __restrict__ rank) {
  int i = blockIdx.x * blockDim.x + threadIdx.x;
  if (i < N_EDGES) {
    int d = dst[i];
    rank[i] = atomicAdd(&cursorPad[d << 4], 1);
  }
}

__global__ __launch_bounds__(256)
void k_compact(const int* __restrict__ cursorPad, int* __restrict__ counts) {
  int i = blockIdx.x * blockDim.x + threadIdx.x;
  if (i < N_NODES_PAD) counts[i] = (i < N_NODES) ? cursorPad[i << 4] : 0;
}

__global__ __launch_bounds__(256)
void k_scanA(const int* __restrict__ counts, int* __restrict__ btot) {
  __shared__ int red[256];
  int t = threadIdx.x;
  const int4* cp = (const int4*)(counts + blockIdx.x * SCAN_CHUNK);
  int4 v = cp[t];
  red[t] = v.x + v.y + v.z + v.w;
  __syncthreads();
  for (int s = 128; s; s >>= 1) {
    if (t < s) red[t] += red[t + s];
    __syncthreads();
  }
  if (t == 0) btot[blockIdx.x] = red[0];
}

__global__ __launch_bounds__(128)
void k_scanB(const int* __restrict__ btot, int* __restrict__ bbase,
             int* __restrict__ offs) {
  __shared__ int part[128];
  int t = threadIdx.x;
  part[t] = (t < SCAN_NB) ? btot[t] : 0;
  __syncthreads();
  for (int o = 1; o < 128; o <<= 1) {
    int v = (t >= o) ? part[t - o] : 0;
    __syncthreads();
    part[t] += v;
    __syncthreads();
  }
  if (t < SCAN_NB) bbase[t] = (t == 0) ? 0 : part[t - 1];
  if (t == 0) offs[N_NODES] = N_EDGES;
}

__global__ __launch_bounds__(256)
void k_scanC(const int* __restrict__ counts, const int* __restrict__ bbase,
             int* __restrict__ offs) {
  __shared__ int part[256];
  int t = threadIdx.x;
  int gbase = blockIdx.x * SCAN_CHUNK;
  const int4* cp = (const int4*)(counts + gbase);
  int4 v = cp[t];
  int tot = v.x + v.y + v.z + v.w;
  part[t] = tot;
  __syncthreads();
  for (int o = 1; o < 256; o <<= 1) {
    int q = (t >= o) ? part[t - o] : 0;
    __syncthreads();
    part[t] += q;
    __syncthreads();
  }
  int run = bbase[blockIdx.x] + part[t] - tot;
  int i0 = gbase + t * 4;
  int o0 = run;
  int o1 = o0 + v.x;
  int o2 = o1 + v.y;
  int o3 = o2 + v.z;
  if (i0 + 0 < N_NODES) offs[i0 + 0] = o0;
  if (i0 + 1 < N_NODES) offs[i0 + 1] = o1;
  if (i0 + 2 < N_NODES) offs[i0 + 2] = o2;
  if (i0 + 3 < N_NODES) offs[i0 + 3] = o3;
}

__global__ __launch_bounds__(256)
void k_scatter(const int* __restrict__ src, const int* __restrict__ dst,
               const int* __restrict__ rank, const int* __restrict__ offs,
               int* __restrict__ csrsrc) {
  int i = blockIdx.x * blockDim.x + threadIdx.x;
  if (i < N_EDGES) {
    csrsrc[offs[dst[i]] + rank[i]] = src[i];
  }
}

// ============== weight transpose to k-contiguous bf16 ==============
__global__ __launch_bounds__(256)
void k_prepw(const float* __restrict__ W1, const float* __restrict__ W2,
             unsigned* __restrict__ W1t32, unsigned* __restrict__ W2t32) {
  int t = threadIdx.x;
  if (blockIdx.x == 0) {
    int c = t;
    const float* wp = W1 + ((c >> 6) << 13) + (c & 63);
    unsigned* op = W1t32 + c * 64;
    for (int fp = 0; fp < 64; ++fp) {
      float lo = wp[(2 * fp) << 6];
      float hi = wp[(2 * fp + 1) << 6];
      op[fp] = packbf2(lo, hi);
    }
  } else {
    int c = t & 63, fq = t >> 6;
    const float* wp = W2 + ((c >> 4) << 12) + (c & 15);
    unsigned* op = W2t32 + c * 128 + fq * 32;
    for (int fp = 0; fp < 32; ++fp) {
      int f0 = fq * 64 + 2 * fp;
      op[fp] = packbf2(wp[f0 << 4], wp[(f0 + 1) << 4]);
    }
  }
}

// ============================ GEMM 1 (MFMA) + fused scores ============================
__global__ __launch_bounds__(256)
void k_gemm1(const float* __restrict__ h, const unsigned short* __restrict__ W1t,
             const float* __restrict__ bias, const float* __restrict__ a1,
             unsigned short* __restrict__ Whb,
             float* __restrict__ sD, float* __restrict__ sS) {
  __shared__ float aLds[512];
  int t = threadIdx.x;
  aLds[t] = a1[t];
  aLds[t + 256] = a1[t + 256];
  __syncthreads();

  int wv = t >> 6;
  int lane = t & 63;
  int m = lane & 15;
  int q8 = (lane >> 4) * 8;
  int node = blockIdx.x * 64 + wv * 16 + m;
  int nclamp = node < N_NODES ? node : N_NODES - 1;

  f32x4_t acc[16] = {};
  const float* hp0 = h + (size_t)nclamp * IN_F + q8;
  #pragma unroll
  for (int ks = 0; ks < 4; ++ks) {
    int kk = ks * 32;
    float4 f0 = *(const float4*)(hp0 + kk);
    float4 f1 = *(const float4*)(hp0 + kk + 4);
    bf16x8_t bf;
    bf[0] = (short)bf16rne(f0.x); bf[1] = (short)bf16rne(f0.y);
    bf[2] = (short)bf16rne(f0.z); bf[3] = (short)bf16rne(f0.w);
    bf[4] = (short)bf16rne(f1.x); bf[5] = (short)bf16rne(f1.y);
    bf[6] = (short)bf16rne(f1.z); bf[7] = (short)bf16rne(f1.w);
    #pragma unroll
    for (int ct = 0; ct < 16; ++ct) {
      bf16x8_t af = *(const bf16x8_t*)(W1t + (ct * 16 + m) * IN_F + kk + q8);
      acc[ct] = __builtin_amdgcn_mfma_f32_16x16x32_bf16(af, bf, acc[ct], 0, 0, 0);
    }
  }
  if (node < N_NODES) {
    unsigned short* op = Whb + (size_t)node * D1;
    int quad4 = (lane >> 4) * 4;
    float pd[4] = {}, ps[4] = {};
    #pragma unroll
    for (int ct = 0; ct < 16; ++ct) {
      int c0 = ct * 16 + quad4;
      float4 bb = *(const float4*)(bias + c0);
      float v0 = acc[ct][0] + bb.x, v1 = acc[ct][1] + bb.y;
      float v2 = acc[ct][2] + bb.z, v3 = acc[ct][3] + bb.w;
      int hh = ct >> 2;
      const float* aD = &aLds[hh * 128 + (c0 & 63)];
      pd[hh] += v0 * aD[0] + v1 * aD[1] + v2 * aD[2] + v3 * aD[3];
      ps[hh] += v0 * aD[64] + v1 * aD[65] + v2 * aD[66] + v3 * aD[67];
      uint2 o;
      o.x = packbf2(v0, v1);
      o.y = packbf2(v2, v3);
      *(uint2*)(op + c0) = o;
    }
    #pragma unroll
    for (int hh = 0; hh < 4; ++hh) {
      pd[hh] += __shfl_xor(pd[hh], 16); pd[hh] += __shfl_xor(pd[hh], 32);
      ps[hh] += __shfl_xor(ps[hh], 16); ps[hh] += __shfl_xor(ps[hh], 32);
    }
    if (lane < 16) {
      ((float4*)sD)[node] = make_float4(pd[0], pd[1], pd[2], pd[3]);
      ((float4*)sS)[node] = make_float4(ps[0], ps[1], ps[2], ps[3]);
    }
  }
}

// ============================ GEMM 2 (MFMA) + fused scores ============================
__global__ __launch_bounds__(256)
void k_gemm2(const unsigned short* __restrict__ h1b, const unsigned short* __restrict__ W2t,
             const float* __restrict__ bias, const float* __restrict__ a2,
             unsigned short* __restrict__ Whb2,
             float* __restrict__ sD, float* __restrict__ sS) {
  __shared__ float aLds[128];
  int t = threadIdx.x;
  if (t < 128) aLds[t] = a2[t];
  __syncthreads();

  int wv = t >> 6;
  int lane = t & 63;
  int m = lane & 15;
  int q8 = (lane >> 4) * 8;
  int node = blockIdx.x * 64 + wv * 16 + m;
  int nclamp = node < N_NODES ? node : N_NODES - 1;

  f32x4_t acc[4] = {};
  const unsigned short* hp0 = h1b + (size_t)nclamp * D1 + q8;
  #pragma unroll
  for (int ks = 0; ks < 8; ++ks) {
    int kk = ks * 32;
    bf16x8_t bf = *(const bf16x8_t*)(hp0 + kk);
    #pragma unroll
    for (int ct = 0; ct < 4; ++ct) {
      bf16x8_t af = *(const bf16x8_t*)(W2t + (ct * 16 + m) * D1 + kk + q8);
      acc[ct] = __builtin_amdgcn_mfma_f32_16x16x32_bf16(af, bf, acc[ct], 0, 0, 0);
    }
  }
  if (node < N_NODES) {
    unsigned short* op = Whb2 + (size_t)node * D2;
    int quad4 = (lane >> 4) * 4;
    float pd[4] = {}, ps[4] = {};
    #pragma unroll
    for (int ct = 0; ct < 4; ++ct) {
      int c0 = ct * 16 + quad4;
      float4 bb = *(const float4*)(bias + c0);
      float v0 = acc[ct][0] + bb.x, v1 = acc[ct][1] + bb.y;
      float v2 = acc[ct][2] + bb.z, v3 = acc[ct][3] + bb.w;
      const float* aD = &aLds[ct * 32 + (c0 & 15)];
      pd[ct] += v0 * aD[0] + v1 * aD[1] + v2 * aD[2] + v3 * aD[3];
      ps[ct] += v0 * aD[16] + v1 * aD[17] + v2 * aD[18] + v3 * aD[19];
      uint2 o;
      o.x = packbf2(v0, v1);
      o.y = packbf2(v2, v3);
      *(uint2*)(op + c0) = o;
    }
    #pragma unroll
    for (int hh = 0; hh < 4; ++hh) {
      pd[hh] += __shfl_xor(pd[hh], 16); pd[hh] += __shfl_xor(pd[hh], 32);
      ps[hh] += __shfl_xor(ps[hh], 16); ps[hh] += __shfl_xor(ps[hh], 32);
    }
    if (lane < 16) {
      ((float4*)sD)[node] = make_float4(pd[0], pd[1], pd[2], pd[3]);
      ((float4*)sS)[node] = make_float4(ps[0], ps[1], ps[2], ps[3]);
    }
  }
}

// ============================ layer-1 aggregate ============================
__device__ __forceinline__ float lrelu(float x) { return x > 0.f ? x : 0.2f * x; }
__device__ __forceinline__ float elu(float x)   { return x > 0.f ? x : expm1f(x); }

// one wave per node; half-wave row split: 32 lanes x 16B cover one 512B row,
// two halves process consecutive edges (2 edges per iteration)
__global__ __launch_bounds__(256)
void k_agg1(const int* __restrict__ offs, const int* __restrict__ csrsrc,
            const float* __restrict__ sD, const float* __restrict__ sS,
            const float* __restrict__ ab,
            const unsigned short* __restrict__ Whb, unsigned short* __restrict__ h1out) {
  __shared__ float exbuf[4][64 * 4];
  __shared__ int   offbuf[4][64];
  int wv = threadIdx.x >> 6;
  int wid = blockIdx.x * 4 + wv;
  int lane = threadIdx.x & 63;
  int g = lane >> 5;          // half index (edge parity)
  int l = lane & 31;          // position within row (16B units)
  int hh = l >> 3;            // head of this lane's 8 feats
  float acc[8] = {};
  float z0 = 0.f, z1 = 0.f, z2 = 0.f, z3 = 0.f;
  int beg = offs[wid], end = offs[wid + 1];
  bool nonempty = end > beg;
  if (nonempty) {
    float4 dv = ((const float4*)sD)[wid];
    float db0 = dv.x + ab[0], db1 = dv.y + ab[1];
    float db2 = dv.z + ab[2], db3 = dv.w + ab[3];
    const float* eb = exbuf[wv];
    const int* ob = offbuf[wv];
    for (int cbeg = beg; cbeg < end; cbeg += 64) {
      int j = cbeg + lane;
      int cnt = end - cbeg; if (cnt > 64) cnt = 64;
      if (j < end) {
        int sid = csrsrc[j];
        float4 sv = ((const float4*)sS)[sid];
        float e0 = __expf(lrelu(db0 + sv.x));
        float e1 = __expf(lrelu(db1 + sv.y));
        float e2 = __expf(lrelu(db2 + sv.z));
        float e3 = __expf(lrelu(db3 + sv.w));
        z0 += e0; z1 += e1; z2 += e2; z3 += e3;
        offbuf[wv][lane] = sid << 9;   // row byte offset
        *(float4*)&exbuf[wv][lane * 4] = make_float4(e0, e1, e2, e3);
      }
      int iters = (cnt + 1) >> 1;
      for (int it = 0; it < iters; ++it) {
        int qq = 2 * it + g;
        int idx = qq < cnt ? qq : cnt - 1;
        float w = eb[idx * 4 + hh];
        if (qq >= cnt) w = 0.f;
        int off = ob[idx];
        uint4 p = *(const uint4*)((const char*)Whb + off + (l << 4));
        acc[0] = fmaf(w, __uint_as_float(p.x << 16), acc[0]);
        acc[1] = fmaf(w, __uint_as_float(p.x), acc[1]);
        acc[2] = fmaf(w, __uint_as_float(p.y << 16), acc[2]);
        acc[3] = fmaf(w, __uint_as_float(p.y), acc[3]);
        acc[4] = fmaf(w, __uint_as_float(p.z << 16), acc[4]);
        acc[5] = fmaf(w, __uint_as_float(p.z), acc[5]);
        acc[6] = fmaf(w, __uint_as_float(p.w << 16), acc[6]);
        acc[7] = fmaf(w, __uint_as_float(p.w), acc[7]);
      }
    }
    #pragma unroll
    for (int o = 32; o; o >>= 1) {
      z0 += __shfl_xor(z0, o);
      z1 += __shfl_xor(z1, o);
      z2 += __shfl_xor(z2, o);
      z3 += __shfl_xor(z3, o);
    }
  }
  // combine edge-parity halves
  #pragma unroll
  for (int i = 0; i < 8; ++i) acc[i] += __shfl_xor(acc[i], 32);
  float z = (hh == 0) ? z0 : (hh == 1) ? z1 : (hh == 2) ? z2 : z3;
  if (!nonempty) z = 1.f;
  float inv = 1.f / z;
  if (g == 0) {
    float e0 = elu(acc[0] * inv), e1 = elu(acc[1] * inv);
    float e2 = elu(acc[2] * inv), e3 = elu(acc[3] * inv);
    float e4 = elu(acc[4] * inv), e5 = elu(acc[5] * inv);
    float e6 = elu(acc[6] * inv), e7 = elu(acc[7] * inv);
    uint4 o;
    o.x = packbf2(e0, e1);
    o.y = packbf2(e2, e3);
    o.z = packbf2(e4, e5);
    o.w = packbf2(e6, e7);
    *(uint4*)(h1out + (size_t)wid * D1 + l * 8) = o;
  }
}

// ============================ layer-2 aggregate + softmax + partial mean ====
// quarter-wave row split: 16 lanes x 8B cover one 128B row, 4 edges per iteration
__global__ __launch_bounds__(256)
void k_agg2(const int* __restrict__ offs, const int* __restrict__ csrsrc,
            const float* __restrict__ sD, const float* __restrict__ sS,
            const float* __restrict__ ab,
            const unsigned short* __restrict__ Whb2, float* __restrict__ partials) {
  __shared__ float exbuf[4][64 * 4];
  __shared__ int   offbuf[4][64];
  __shared__ float red[4][16];
  int wv = threadIdx.x >> 6;
  int wid = blockIdx.x * 4 + wv;
  int lane = threadIdx.x & 63;
  int g = lane >> 4;          // quarter index (edge offset)
  int l = lane & 15;          // position within row (8B units)
  int hh = l >> 2;            // head of this lane's 4 feats
  float acc[4] = {};
  float z0 = 0.f, z1 = 0.f, z2 = 0.f, z3 = 0.f;
  int beg = offs[wid], end = offs[wid + 1];
  bool nonempty = end > beg;
  if (nonempty) {
    float4 dv = ((const float4*)sD)[wid];
    float db0 = dv.x + ab[0], db1 = dv.y + ab[1];
    float db2 = dv.z + ab[2], db3 = dv.w + ab[3];
    const float* eb = exbuf[wv];
    const int* ob = offbuf[wv];
    for (int cbeg = beg; cbeg < end; cbeg += 64) {
      int j = cbeg + lane;
      int cnt = end - cbeg; if (cnt > 64) cnt = 64;
      if (j < end) {
        int sid = csrsrc[j];
        float4 sv = ((const float4*)sS)[sid];
        float e0 = __expf(lrelu(db0 + sv.x));
        float e1 = __expf(lrelu(db1 + sv.y));
        float e2 = __expf(lrelu(db2 + sv.z));
        float e3 = __expf(lrelu(db3 + sv.w));
        z0 += e0; z1 += e1; z2 += e2; z3 += e3;
        offbuf[wv][lane] = sid << 7;   // row byte offset
        *(float4*)&exbuf[wv][lane * 4] = make_float4(e0, e1, e2, e3);
      }
      int iters = (cnt + 3) >> 2;
      for (int it = 0; it < iters; ++it) {
        int qq = 4 * it + g;
        int idx = qq < cnt ? qq : cnt - 1;
        float w = eb[idx * 4 + hh];
        if (qq >= cnt) w = 0.f;
        int off = ob[idx];
        uint2 p = *(const uint2*)((const char*)Whb2 + off + (l << 3));
        acc[0] = fmaf(w, __uint_as_float(p.x << 16), acc[0]);
        acc[1] = fmaf(w, __uint_as_float(p.x), acc[1]);
        acc[2] = fmaf(w, __uint_as_float(p.y << 16), acc[2]);
        acc[3] = fmaf(w, __uint_as_float(p.y), acc[3]);
      }
    }
    #pragma unroll
    for (int s = 32; s; s >>= 1) {
      z0 += __shfl_xor(z0, s);
      z1 += __shfl_xor(z1, s);
      z2 += __shfl_xor(z2, s);
      z3 += __shfl_xor(z3, s);
    }
  }
  // combine edge quarters
  #pragma unroll
  for (int i = 0; i < 4; ++i) {
    acc[i] += __shfl_xor(acc[i], 16);
    acc[i] += __shfl_xor(acc[i], 32);
  }
  float z = (hh == 0) ? z0 : (hh == 1) ? z1 : (hh == 2) ? z2 : z3;
  if (!nonempty) z = 1.f;
  float inv = 1.f / z;
  float val[4];
  #pragma unroll
  for (int i = 0; i < 4; ++i) val[i] = acc[i] * inv;
  // head mean: lanes l, l^4, l^8, l^12 hold same classes for different heads
  #pragma unroll
  for (int i = 0; i < 4; ++i) {
    val[i] += __shfl_xor(val[i], 4);
    val[i] += __shfl_xor(val[i], 8);
    val[i] *= 0.25f;
  }
  // softmax over 16 classes spread across lanes (l&3) x 4 regs
  float mx = fmaxf(fmaxf(val[0], val[1]), fmaxf(val[2], val[3]));
  mx = fmaxf(mx, __shfl_xor(mx, 1));
  mx = fmaxf(mx, __shfl_xor(mx, 2));
  float e[4];
  float ssum = 0.f;
  #pragma unroll
  for (int i = 0; i < 4; ++i) { e[i] = __expf(val[i] - mx); ssum += e[i]; }
  ssum += __shfl_xor(ssum, 1);
  ssum += __shfl_xor(ssum, 2);
  float rinv = 1.f / ssum;
  if (g == 0 && l < 4) {
    #pragma unroll
    for (int i = 0; i < 4; ++i) red[wv][l * 4 + i] = e[i] * rinv;
  }
  __syncthreads();
  if (threadIdx.x < 16) {
    partials[(size_t)blockIdx.x * 16 + threadIdx.x] =
        red[0][threadIdx.x] + red[1][threadIdx.x] +
        red[2][threadIdx.x] + red[3][threadIdx.x];
  }
}

// ============== hierarchical final reduce: 25000 -> 128 -> fc ==============
__global__ __launch_bounds__(256)
void k_reduce1(const float* __restrict__ partials, int nrows,
               float* __restrict__ out) {
  __shared__ float red[16][17];
  int t = threadIdx.x;
  int c = t & 15, rl = t >> 4;
  int per = (nrows + RB1 - 1) / RB1;
  int rbeg = blockIdx.x * per;
  int rend = rbeg + per; if (rend > nrows) rend = nrows;
  float s = 0.f;
  for (int r = rbeg + rl; r < rend; r += 16) s += partials[(size_t)r * 16 + c];
  red[rl][c] = s;
  __syncthreads();
  for (int st = 8; st; st >>= 1) {
    if (rl < st) red[rl][c] += red[rl + st][c];
    __syncthreads();
  }
  if (t < 16) out[(size_t)blockIdx.x * 16 + t] = red[0][t];
}

__global__ __launch_bounds__(256)
void k_final(const float* __restrict__ partials,
             const float* __restrict__ fcw, const float* __restrict__ fcb,
             float* __restrict__ out) {
  __shared__ float red[16][17];
  __shared__ float hg[16];
  int t = threadIdx.x;
  int c = t & 15, rl = t >> 4;
  float s = 0.f;
  for (int r = rl; r < RB1; r += 16) s += partials[(size_t)r * 16 + c];
  red[rl][c] = s;
  __syncthreads();
  for (int st = 8; st; st >>= 1) {
    if (rl < st) red[rl][c] += red[rl + st][c];
    __syncthreads();
  }
  if (t < 16) hg[t] = red[0][t] * (1.0f / N_NODES);
  __syncthreads();
  if (t < 16) {
    float acc = fcb[t];
    #pragma unroll
    for (int k = 0; k < 16; ++k) acc += hg[k] * fcw[t * 16 + k];
    out[t] = acc;
  }
}

// ============================ launcher ============================
extern "C" void kernel_launch(void* const* d_in, const int* in_sizes, int n_in,
                              void* d_out, int out_size, void* d_ws, size_t ws_size,
                              hipStream_t stream) {
  const float* h   = (const float*)d_in[0];
  const int*   src = (const int*)  d_in[1];
  const int*   dst = (const int*)  d_in[2];
  const float* W1  = (const float*)d_in[3];
  const float* b1  = (const float*)d_in[4];
  const float* a1  = (const float*)d_in[5];
  const float* ab1 = (const float*)d_in[6];
  const float* W2  = (const float*)d_in[7];
  const float* b2  = (const float*)d_in[8];
  const float* a2  = (const float*)d_in[9];
  const float* ab2 = (const float*)d_in[10];
  const float* fcw = (const float*)d_in[11];
  const float* fcb = (const float*)d_in[12];
  float* out = (float*)d_out;

  char* ws = (char*)d_ws;
  size_t off = 0;
  auto alloc = [&](size_t bytes) -> char* {
    char* p = ws + off;
    off += (bytes + 255) & ~(size_t)255;
    return p;
  };
  unsigned short* Whb1 = (unsigned short*)alloc((size_t)N_NODES * D1 * 2); // 51.2 MB
  unsigned short* h1b  = (unsigned short*)alloc((size_t)N_NODES * D1 * 2); // 51.2 MB
  unsigned short* Whb2 = (unsigned short*)alloc((size_t)N_NODES * D2 * 2); // 12.8 MB
  unsigned short* W1t  = (unsigned short*)alloc((size_t)D1 * IN_F * 2);
  unsigned short* W2t  = (unsigned short*)alloc((size_t)D2 * D1 * 2);
  float* sD1 = (float*)alloc((size_t)N_NODES * 4 * 4);
  float* sS1 = (float*)alloc((size_t)N_NODES * 4 * 4);
  float* sD2 = (float*)alloc((size_t)N_NODES * 4 * 4);
  float* sS2 = (float*)alloc((size_t)N_NODES * 4 * 4);
  int* cursorPad = (int*)alloc((size_t)N_NODES * 16 * 4);   // 6.4 MB
  int* rank   = (int*)alloc((size_t)N_EDGES * 4);           // 6.4 MB
  int* counts = (int*)alloc((size_t)N_NODES_PAD * 4);
  int* offs   = (int*)alloc((size_t)(N_NODES + 1) * 4);
  int* csrsrc = (int*)alloc((size_t)N_EDGES * 4);
  int* btot   = (int*)alloc((size_t)SCAN_NB * 4);
  int* bbase  = (int*)alloc((size_t)SCAN_NB * 4);
  const int nblk_node = (N_NODES + 3) / 4;   // 25000
  float* partials  = (float*)alloc((size_t)nblk_node * 16 * 4);
  float* partials2 = (float*)alloc((size_t)RB1 * 16 * 4);

  // --- weight transpose (bf16, k-contiguous) ---
  k_prepw<<<2, 256, 0, stream>>>(W1, W2, (unsigned*)W1t, (unsigned*)W2t);

  // --- CSR build (by dst); atomic-free scatter via fetch-add rank ---
  const int n4 = N_NODES * 4;
  k_zero4<<<(n4 + 255) / 256, 256, 0, stream>>>((int4*)cursorPad, n4);
  k_count<<<(N_EDGES + 255) / 256, 256, 0, stream>>>(dst, cursorPad, rank);
  k_compact<<<(N_NODES_PAD + 255) / 256, 256, 0, stream>>>(cursorPad, counts);
  k_scanA<<<SCAN_NB, 256, 0, stream>>>(counts, btot);
  k_scanB<<<1, 128, 0, stream>>>(btot, bbase, offs);
  k_scanC<<<SCAN_NB, 256, 0, stream>>>(counts, bbase, offs);
  k_scatter<<<(N_EDGES + 255) / 256, 256, 0, stream>>>(src, dst, rank, offs, csrsrc);

  const int gemmBlocks = (N_NODES + 63) / 64;   // 1563

  // --- layer 1 ---
  k_gemm1<<<gemmBlocks, 256, 0, stream>>>(h, W1t, b1, a1, Whb1, sD1, sS1);
  k_agg1<<<nblk_node, 256, 0, stream>>>(offs, csrsrc, sD1, sS1, ab1, Whb1, h1b);

  // --- layer 2 ---
  k_gemm2<<<gemmBlocks, 256, 0, stream>>>(h1b, W2t, b2, a2, Whb2, sD2, sS2);
  k_agg2<<<nblk_node, 256, 0, stream>>>(offs, csrsrc, sD2, sS2, ab2, Whb2, partials);

  // --- readout ---
  k_reduce1<<<RB1, 256, 0, stream>>>(partials, nblk_node, partials2);
  k_final<<<1, 256, 0, stream>>>(partials2, fcw, fcb, out);
}